// Round 17
// baseline (628.035 us; speedup 1.0000x reference)
//
#include <hip/hip_runtime.h>
#include <stdint.h>
#include <math.h>

// ---------- types / helpers ----------
typedef _Float16 f16x8 __attribute__((ext_vector_type(8)));
typedef float    f32x4 __attribute__((ext_vector_type(4)));
typedef __attribute__((address_space(1))) void as1_void;
typedef __attribute__((address_space(3))) void as3_void;

__device__ __forceinline__ unsigned short f2h(float x) {
    _Float16 h = (_Float16)x;
    return __builtin_bit_cast(unsigned short, h);
}
__device__ __forceinline__ float h2f(unsigned short u) {
    return (float)__builtin_bit_cast(_Float16, u);
}
// async global->LDS, 16B/lane; lds dest must be wave-uniform base (HW adds lane*16)
__device__ __forceinline__ void glds16(const void* g, void* l) {
    __builtin_amdgcn_global_load_lds((as1_void*)g, (as3_void*)l, 16, 0, 0);
}

// 16-lane DPP butterfly step (VALU-speed, avoids ds_swizzle latency of __shfl_xor):
// 0xB1 = quad_perm(1,0,3,2) ~ xor1 ; 0x4E = quad_perm(2,3,0,1) ~ xor2 ;
// 0x141 = row_half_mirror (pairs across quads within 8) ; 0x128 = row_ror:8 ~ xor8.
#define DPPF(v, ctrl) __builtin_bit_cast(float, \
    __builtin_amdgcn_update_dpp(0, __builtin_bit_cast(int, (v)), (ctrl), 0xF, 0xF, true))

// B=2, S=2048, Hid=2048, NH=16, NKV=4, D=128, chunks: 8 x 256, TOPK=4
//
// R15 fusions (bit-exact; 11 -> 8 launches): fused0 = setup|split|packall,
// fusedrk = repair|kvprep.
// R16: attn drops V-staging — PV reads V^T directly from global (per-lane
// 16B aligned loads, L2-resident 8MB working set; guide m169 analog).
// Halves the per-subtile LDS write volume the barrier drains; -16 VGPR.
// Gate strategy (margin-filtered repair):
//  - exact fp64 kmean via rope-factorization (ksum/kmeanw)
//  - provisional gates from fp16-MFMA q vs exact km64 (fused into ropegate;
//    8-lane-group reduce — R11); margin < TAU -> fp64 repair, h-bucketed
// Value path: fp16 MFMA QKV GEMM (global_load_lds staging), fused fp32
// rope+gates, fp16 MFMA flash attn (K LDS-staged + register prefetch,
// DPP row-reduce softmax; 16 rows/wave = 3 blocks/CU; R13 wave-level
// subtile skip, bit-exact, barrier-safe), fp16 out-proj.
//
// VGPR discipline (R3+R10): live-VGPR must fit 512/(waves-per-EU bound);
// spill signature = WRITE_SIZE blowup + forced-low VGPR_Count.

#define TAU 0.015
#define FLAGCAP 4096

// ---------- fused0: setup | split | packall ----------
// grid: [0,512) setup ; [512,8704) split ; [8704,18944) packall
__global__ __launch_bounds__(256)
void fused0_kernel(float* __restrict__ ct, float* __restrict__ st,
                   double* __restrict__ km, int* __restrict__ flagcnt,
                   const float* __restrict__ hs, unsigned short* __restrict__ hsh,
                   const float* __restrict__ wq, const float* __restrict__ wk,
                   const float* __restrict__ wv, const float* __restrict__ wo,
                   unsigned short* __restrict__ Wh, unsigned short* __restrict__ Woh) {
    int bid = blockIdx.x;
    int t = threadIdx.x;
    if (bid < 512) {
        // ---- setup: CR-fp32 sincos tables + zero km64 + zero flag counters
        int gid = bid * 256 + t;            // 512*256 = 2048*64
        if (gid < 16) flagcnt[gid] = 0;
        if (gid < 8192) km[gid] = 0.0;
        int i = gid & 63, s = gid >> 6;
        float xf = (float)i * (1.0f / 64.0f);
        float pf = (float)pow(10000.0, (double)xf);     // CR fp32 pow
        float inv = 1.0f / pf;                          // second fp32 rounding (np)
        float ang = (float)s * inv;
        ct[gid] = (float)cos((double)ang);
        st[gid] = (float)sin((double)ang);
    } else if (bid < 8704) {
        // ---- split: hs fp32 -> fp16 (2097152 float4 groups)
        int i = (bid - 512) * 256 + t;
        if (i >= 2097152) return;
        float4 v = ((const float4*)hs)[i];
        ushort4 h;
        h.x = f2h(v.x); h.y = f2h(v.y); h.z = f2h(v.z); h.w = f2h(v.w);
        ((ushort4*)hsh)[i] = h;
    } else {
        // ---- packall: [wq|wk|wv]^T -> Wh[n][k], wo^T -> Woh[n][k], fp16
        int gid = (bid - 8704) * 256 + t;
        if (gid < 3072 * 512) {
            int n  = gid % 3072;
            int kg = gid / 3072;
            const float* src; int ldn, col;
            if (n < 2048)      { src = wq; ldn = 2048; col = n; }
            else if (n < 2560) { src = wk; ldn = 512;  col = n - 2048; }
            else               { src = wv; ldn = 512;  col = n - 2560; }
            int k0 = kg * 4;
            ushort4 h;
            h.x = f2h(src[(size_t)(k0 + 0) * ldn + col]);
            h.y = f2h(src[(size_t)(k0 + 1) * ldn + col]);
            h.z = f2h(src[(size_t)(k0 + 2) * ldn + col]);
            h.w = f2h(src[(size_t)(k0 + 3) * ldn + col]);
            *(ushort4*)&Wh[(size_t)n * 2048 + k0] = h;
        } else {
            int g2 = gid - 3072 * 512;   // 2048*512
            int n  = g2 % 2048;
            int kg = g2 / 2048;
            int k0 = kg * 4;
            ushort4 h;
            h.x = f2h(wo[(size_t)(k0 + 0) * 2048 + n]);
            h.y = f2h(wo[(size_t)(k0 + 1) * 2048 + n]);
            h.z = f2h(wo[(size_t)(k0 + 2) * 2048 + n]);
            h.w = f2h(wo[(size_t)(k0 + 3) * 2048 + n]);
            *(ushort4*)&Woh[(size_t)n * 2048 + k0] = h;
        }
    }
}

// ---------- trig-weighted chunk sums: Act/Ast[bn][h][d] (fp64) ----------
__global__ __launch_bounds__(256)
void ksum_kernel(const float* __restrict__ hs, const float* __restrict__ ct,
                 const float* __restrict__ st, double* __restrict__ Act,
                 double* __restrict__ Ast) {
    __shared__ float Hs[16][68];
    __shared__ float Tc[16][68];
    __shared__ float Ts[16][68];
    int bn = blockIdx.y;             // b*8 + n
    int h0 = blockIdx.x * 64;
    int b = bn >> 3, n = bn & 7;
    int t = threadIdx.x;
    int tx = t & 15, ty = t >> 4;
    int d0 = tx * 4, hl0 = ty * 4;
    int si = t & 15, g4 = (t >> 4) * 4;
    double ac[4][4] = {}, as_[4][4] = {};
    for (int s0 = 0; s0 < 256; s0 += 16) {
        __syncthreads();
        int srow = n * 256 + s0 + si;
        *(float4*)&Hs[si][g4] = *(const float4*)&hs[(size_t)(b * 2048 + srow) * 2048 + h0 + g4];
        *(float4*)&Tc[si][g4] = *(const float4*)&ct[srow * 64 + g4];
        *(float4*)&Ts[si][g4] = *(const float4*)&st[srow * 64 + g4];
        __syncthreads();
        #pragma unroll
        for (int kk = 0; kk < 16; ++kk) {
            double hv[4], cv[4], sv[4];
            #pragma unroll
            for (int j = 0; j < 4; ++j) hv[j] = (double)Hs[kk][hl0 + j];
            #pragma unroll
            for (int i = 0; i < 4; ++i) { cv[i] = (double)Tc[kk][d0 + i]; sv[i] = (double)Ts[kk][d0 + i]; }
            #pragma unroll
            for (int i = 0; i < 4; ++i)
                #pragma unroll
                for (int j = 0; j < 4; ++j) {
                    ac[i][j]  = fma(cv[i], hv[j], ac[i][j]);
                    as_[i][j] = fma(sv[i], hv[j], as_[i][j]);
                }
        }
    }
    #pragma unroll
    for (int j = 0; j < 4; ++j) {
        size_t rb = ((size_t)bn * 2048 + h0 + hl0 + j) * 64 + d0;
        double2 c0 = {ac[0][j], ac[1][j]},  c1 = {ac[2][j], ac[3][j]};
        double2 s0_ = {as_[0][j], as_[1][j]}, s1_ = {as_[2][j], as_[3][j]};
        *(double2*)&Act[rb] = c0; *(double2*)&Act[rb + 2] = c1;
        *(double2*)&Ast[rb] = s0_; *(double2*)&Ast[rb + 2] = s1_;
    }
}

// ---------- contract Act/Ast with wk -> exact km64 ----------
__global__ __launch_bounds__(256)
void kmeanw_kernel(const double* __restrict__ Act, const double* __restrict__ Ast,
                   const float* __restrict__ wk, double* __restrict__ km) {
    __shared__ double red[256];
    int blk = blockIdx.x;            // ((bn*4 + kvh)*32 + hp)
    int hp = blk & 31, kvh = (blk >> 5) & 3, bn = blk >> 7;
    int t = threadIdx.x;
    int d = t & 127, sub = t >> 7;
    int jj = d & 63;
    int col1 = kvh * 128 + d;
    int col2 = kvh * 128 + (d ^ 64);
    double sgn = (d < 64) ? -1.0 : 1.0;
    const double* actb = Act + (size_t)bn * 2048 * 64;
    const double* astb = Ast + (size_t)bn * 2048 * 64;
    double a1 = 0.0, a2 = 0.0, b1 = 0.0, b2 = 0.0;
    double c1 = 0.0, c2 = 0.0, d1 = 0.0, d2 = 0.0;
    int hbeg = hp * 64 + sub * 32;   // 32 hp x 64 + 2 sub x 32 covers [0,2048)
    #pragma unroll 2
    for (int h = hbeg; h < hbeg + 32; h += 4) {
        a1 = fma(actb[(size_t)(h + 0) * 64 + jj], (double)wk[(size_t)(h + 0) * 512 + col1], a1);
        a2 = fma(astb[(size_t)(h + 0) * 64 + jj], (double)wk[(size_t)(h + 0) * 512 + col2], a2);
        b1 = fma(actb[(size_t)(h + 1) * 64 + jj], (double)wk[(size_t)(h + 1) * 512 + col1], b1);
        b2 = fma(astb[(size_t)(h + 1) * 64 + jj], (double)wk[(size_t)(h + 1) * 512 + col2], b2);
        c1 = fma(actb[(size_t)(h + 2) * 64 + jj], (double)wk[(size_t)(h + 2) * 512 + col1], c1);
        c2 = fma(astb[(size_t)(h + 2) * 64 + jj], (double)wk[(size_t)(h + 2) * 512 + col2], c2);
        d1 = fma(actb[(size_t)(h + 3) * 64 + jj], (double)wk[(size_t)(h + 3) * 512 + col1], d1);
        d2 = fma(astb[(size_t)(h + 3) * 64 + jj], (double)wk[(size_t)(h + 3) * 512 + col2], d2);
    }
    double acc1 = (a1 + b1) + (c1 + d1);
    double acc2 = (a2 + b2) + (c2 + d2);
    red[t] = acc1 + sgn * acc2;
    __syncthreads();
    if (t < 128) {
        double v = red[t] + red[t + 128];
        atomicAdd(&km[((size_t)bn * 4 + kvh) * 128 + d], v * (1.0 / 256.0));
    }
}

// ---------- fused rope (q,k in-place) + provisional fp64 gates + margin flags ----
// R11: 8-lane-group-per-chunk reduce, 3-step butterfly + 8 gathers.
__global__ __launch_bounds__(256)
void ropegate_kernel(float* __restrict__ C, const float* __restrict__ ct,
                     const float* __restrict__ st, const double* __restrict__ km,
                     unsigned int* __restrict__ maskbuf,
                     int* __restrict__ flagcnt, int* __restrict__ flaglist) {
    __shared__ float qbuf[2048];
    int bs = blockIdx.x;             // b*2048 + s
    int s = bs & 2047, b = bs >> 11;
    int t = threadIdx.x;
    size_t base = (size_t)bs * 3072;
    #pragma unroll
    for (int it = 0; it < 5; ++it) {  // 20 heads x 64 pairs = 1280 = 5*256
        int p = t + it * 256;
        int hd = p >> 6, i = p & 63;
        float cs = ct[s * 64 + i], sn = st[s * 64 + i];
        float x1 = C[base + hd * 128 + i];
        float x2 = C[base + hd * 128 + i + 64];
        float n1 = x1 * cs - x2 * sn;
        float n2 = x2 * cs + x1 * sn;
        C[base + hd * 128 + i] = n1;
        C[base + hd * 128 + i + 64] = n2;
        if (hd < 16) { qbuf[hd * 128 + i] = n1; qbuf[hd * 128 + i + 64] = n2; }
    }
    __syncthreads();
    int wave = t >> 6, lane = t & 63;
    int grp = lane >> 3, j = lane & 7;   // group -> chunk n, j -> d sub-lane
    int qc = s >> 8;
    const double INF = __builtin_inf();
    #pragma unroll
    for (int ii = 0; ii < 4; ++ii) {
        int h = wave * 4 + ii;
        int kvh = h >> 2;
        size_t kb = (size_t)((b * 8 + grp) * 4 + kvh) * 128;
        const float* qh = qbuf + h * 128;
        double acc0 = 0.0, acc1 = 0.0;
        #pragma unroll
        for (int i = 0; i < 8; ++i) {
            int d = j + 8 * i;
            acc0 = fma((double)qh[d],      km[kb + d],      acc0);
            acc1 = fma((double)qh[d + 64], km[kb + 64 + d], acc1);
        }
        double acc = acc0 + acc1;
        // 3-step butterfly within the 8-lane group (chunk-local sum)
        acc += __shfl_xor(acc, 1);
        acc += __shfl_xor(acc, 2);
        acc += __shfl_xor(acc, 4);
        // gather group sums: g[n] lives in lanes n*8..n*8+7
        double g[8];
        #pragma unroll
        for (int n = 0; n < 8; ++n) g[n] = __shfl(acc, n * 8);
        #pragma unroll
        for (int n = 0; n < 8; ++n) {
            if (n == qc)                g[n] = INF;
            else if (s < (n + 1) * 256) g[n] = -INF;
        }
        unsigned int msk = 0;
        for (int p = 0; p < 4; ++p) {  // iterative argmax; strict > => lowest idx on ties
            double best = -INF; int bi = -1;
            #pragma unroll
            for (int n = 0; n < 8; ++n)
                if (!((msk >> n) & 1) && g[n] > best) { best = g[n]; bi = n; }
            if (bi >= 0) msk |= 1u << bi;
        }
        if (lane == 0) {
            int wid = ((b * 16 + h) << 11) + s;
            maskbuf[wid] = msk;
            if (qc >= 4) {
                double worst_in = INF, best_out = -INF;
                #pragma unroll
                for (int n = 0; n < 8; ++n) {
                    if ((msk >> n) & 1) worst_in = fmin(worst_in, g[n]);
                    else if (g[n] > -1e300) best_out = fmax(best_out, g[n]);
                }
                if (worst_in - best_out < TAU) {
                    int ix = atomicAdd(&flagcnt[h], 1);
                    if (ix < FLAGCAP) flaglist[h * FLAGCAP + ix] = wid;
                }
            }
        }
    }
}

// ---------- fusedrk: repair (h-bucketed) | kvprep ----------
// grid: [0,4096) repair ; [4096,4352) kvprep. LDS union = 25856B (repair's
// footprint) -> repair occupancy unchanged; kvprep's 18432B fits inside.
__global__ __launch_bounds__(256)
void fusedrk_kernel(const float* __restrict__ hs, const float* __restrict__ wq,
                    const float* __restrict__ ct, const float* __restrict__ st,
                    const double* __restrict__ km, const int* __restrict__ flagcnt,
                    const int* __restrict__ flaglist, unsigned int* __restrict__ maskbuf,
                    const float* __restrict__ C, unsigned short* __restrict__ Kh,
                    unsigned short* __restrict__ Vt) {
    __shared__ char SH[25856];
    int t = threadIdx.x;
    if (blockIdx.x < 4096) {
        // ---- repair path (R5 ILP + R6 h-bucketing)
        double* hrow_d = (double*)SH;                       // 2048 d = 16384B
        double (*red)[132] = (double(*)[132])(SH + 16384);  // 8x132 d = 8448B
        double* qs = (double*)(SH + 24832);                 // 128 d = 1024B
        int hb = blockIdx.x >> 8;         // 16 head groups x 256 blocks
        int nflag = flagcnt[hb];
        if (nflag > FLAGCAP) nflag = FLAGCAP;
        const int* list = flaglist + hb * FLAGCAP;
        int dg = t & 31, sub = t >> 5;    // d = dg*4..+3 ; k in [sub*256, +256)
        for (int idx = blockIdx.x & 255; idx < nflag; idx += 256) {
            int wid = list[idx];
            int s = wid & 2047;
            int h = (wid >> 11) & 15;
            int b = wid >> 15;
            int kvh = h >> 2;
            __syncthreads();
            {   // cooperative coalesced fp32->fp64 row stage
                const float4* src = (const float4*)(hs + (size_t)(b * 2048 + s) * 2048);
                float4 v0 = src[t], v1 = src[t + 256];
                hrow_d[4 * t + 0] = (double)v0.x; hrow_d[4 * t + 1] = (double)v0.y;
                hrow_d[4 * t + 2] = (double)v0.z; hrow_d[4 * t + 3] = (double)v0.w;
                hrow_d[4 * t + 1024 + 0] = (double)v1.x; hrow_d[4 * t + 1024 + 1] = (double)v1.y;
                hrow_d[4 * t + 1024 + 2] = (double)v1.z; hrow_d[4 * t + 1024 + 3] = (double)v1.w;
            }
            __syncthreads();
            const float* wbase = wq + (size_t)(sub * 256) * 2048 + h * 128 + dg * 4;
            const double* hb_ = hrow_d + sub * 256;
            double a0 = 0, a1 = 0, a2 = 0, a3 = 0;
            double c0 = 0, c1 = 0, c2 = 0, c3 = 0;
            #pragma unroll 4
            for (int k = 0; k < 256; k += 2) {
                float4 w0 = *(const float4*)&wbase[(size_t)k * 2048];
                float4 w1 = *(const float4*)&wbase[(size_t)(k + 1) * 2048];
                double h0 = hb_[k], h1 = hb_[k + 1];
                a0 = fma(h0, (double)w0.x, a0); a1 = fma(h0, (double)w0.y, a1);
                a2 = fma(h0, (double)w0.z, a2); a3 = fma(h0, (double)w0.w, a3);
                c0 = fma(h1, (double)w1.x, c0); c1 = fma(h1, (double)w1.y, c1);
                c2 = fma(h1, (double)w1.z, c2); c3 = fma(h1, (double)w1.w, c3);
            }
            red[sub][dg * 4 + 0] = a0 + c0; red[sub][dg * 4 + 1] = a1 + c1;
            red[sub][dg * 4 + 2] = a2 + c2; red[sub][dg * 4 + 3] = a3 + c3;
            __syncthreads();
            if (t < 128) {
                double v = 0.0;
                #pragma unroll
                for (int u = 0; u < 8; ++u) v += red[u][t];
                qs[t] = v;
            }
            __syncthreads();
            if (t < 64) {
                double c  = (double)ct[s * 64 + t];
                double sn = (double)st[s * 64 + t];
                double x1 = qs[t], x2 = qs[t + 64];
                qs[t]      = x1 * c - x2 * sn;
                qs[t + 64] = x2 * c + x1 * sn;
            }
            __syncthreads();
            if (t < 64) {
                double g[8];
                #pragma unroll
                for (int n = 0; n < 8; ++n) {
                    size_t kb = (size_t)((b * 8 + n) * 4 + kvh) * 128;
                    double v = qs[t] * km[kb + t] + qs[t + 64] * km[kb + 64 + t];
                    #pragma unroll
                    for (int off = 32; off; off >>= 1) v += __shfl_xor(v, off);
                    g[n] = v;
                }
                int qc = s >> 8;
                const double INF = __builtin_inf();
                #pragma unroll
                for (int n = 0; n < 8; ++n) {
                    if (n == qc)                g[n] = INF;
                    else if (s < (n + 1) * 256) g[n] = -INF;
                }
                unsigned int msk = 0;
                for (int p = 0; p < 4; ++p) {
                    double best = -INF; int bi = -1;
                    #pragma unroll
                    for (int n = 0; n < 8; ++n)
                        if (!((msk >> n) & 1) && g[n] > best) { best = g[n]; bi = n; }
                    if (bi >= 0) msk |= 1u << bi;
                }
                if (t == 0) maskbuf[wid] = msk;
            }
            __syncthreads();
        }
    } else {
        // ---- kvprep path: K -> fp16 row-major, V -> fp16 transposed
        unsigned short (*vt)[72] = (unsigned short(*)[72])SH;   // 128x72 us = 18432B
        int blk = blockIdx.x - 4096;   // (b*4+kvh)*32 + kt
        int kt = blk & 31, kvh = (blk >> 5) & 3, b = blk >> 7;
        int key0 = kt * 64;
        #pragma unroll
        for (int it = 0; it < 8; ++it) {
            int idx = t + it * 256;
            int r = idx >> 5, c = (idx & 31) * 4;
            size_t rowb = (size_t)(b * 2048 + key0 + r) * 3072;
            float4 kv = *(const float4*)&C[rowb + 2048 + kvh * 128 + c];
            ushort4 u; u.x = f2h(kv.x); u.y = f2h(kv.y); u.z = f2h(kv.z); u.w = f2h(kv.w);
            *(ushort4*)&Kh[((size_t)(b * 4 + kvh) * 2048 + key0 + r) * 128 + c] = u;
            float4 vv = *(const float4*)&C[rowb + 2560 + kvh * 128 + c];
            vt[c + 0][r] = f2h(vv.x); vt[c + 1][r] = f2h(vv.y);
            vt[c + 2][r] = f2h(vv.z); vt[c + 3][r] = f2h(vv.w);
        }
        __syncthreads();
        #pragma unroll
        for (int it = 0; it < 8; ++it) {
            int idx = t + it * 256;
            int d = idx >> 4, c4 = (idx & 15) * 4;
            *(ushort4*)&Vt[((size_t)(b * 4 + kvh) * 128 + d) * 2048 + key0 + c4] =
                *(ushort4*)&vt[d][c4];
        }
    }
}

// ---------- fp16 MFMA GEMM, m97-style global_load_lds staging ----------
// A row-major [m][k]; B pre-transposed [n][k]; unpadded LDS tiles [128][32].
__global__ __launch_bounds__(256, 2)
void gemm_kernel(const unsigned short* __restrict__ A_g, const unsigned short* __restrict__ B_g,
                 float* __restrict__ Cg, int M, int N, int K) {
    __shared__ unsigned short Ah[128 * 32];
    __shared__ unsigned short Bh[128 * 32];
    int n0 = blockIdx.x * 128, m0 = blockIdx.y * 128;
    int t = threadIdx.x;
    int wave = t >> 6, lane = t & 63;
    int quad = lane >> 4, l15 = lane & 15;
    int wm = (wave >> 1) * 64, wn = (wave & 1) * 64;

    f32x4 acc[4][4];
    f32x4 zero = {0.f, 0.f, 0.f, 0.f};
    for (int i = 0; i < 4; ++i)
        for (int j = 0; j < 4; ++j) acc[i][j] = zero;

    // staging: lane covers row (lane>>2), 8 halves at col (lane&3)*8 of a 16-row segment
    int srow = lane >> 2, scol = (lane & 3) * 8;
    const unsigned short* Ag0 = &A_g[(size_t)(m0 + wave * 16 + srow) * K + scol];
    const unsigned short* Ag1 = &A_g[(size_t)(m0 + 64 + wave * 16 + srow) * K + scol];
    const unsigned short* Bg0 = &B_g[(size_t)(n0 + wave * 16 + srow) * K + scol];
    const unsigned short* Bg1 = &B_g[(size_t)(n0 + 64 + wave * 16 + srow) * K + scol];
    unsigned short* Al0 = &Ah[(wave * 16) * 32];
    unsigned short* Al1 = &Ah[(64 + wave * 16) * 32];
    unsigned short* Bl0 = &Bh[(wave * 16) * 32];
    unsigned short* Bl1 = &Bh[(64 + wave * 16) * 32];

    for (int k0 = 0; k0 < K; k0 += 32) {
        __syncthreads();
        glds16(Ag0 + k0, Al0);
        glds16(Ag1 + k0, Al1);
        glds16(Bg0 + k0, Bl0);
        glds16(Bg1 + k0, Bl1);
        __syncthreads();   // drains vmcnt -> staging visible
        f16x8 ah[4], bh[4];
        #pragma unroll
        for (int i = 0; i < 4; ++i) {
            ah[i] = *(const f16x8*)&Ah[(wm + i * 16 + l15) * 32 + quad * 8];
            bh[i] = *(const f16x8*)&Bh[(wn + i * 16 + l15) * 32 + quad * 8];
        }
        #pragma unroll
        for (int i = 0; i < 4; ++i)
            #pragma unroll
            for (int j = 0; j < 4; ++j)
                acc[i][j] = __builtin_amdgcn_mfma_f32_16x16x32_f16(ah[i], bh[j], acc[i][j], 0, 0, 0);
    }
    #pragma unroll
    for (int i = 0; i < 4; ++i)
        #pragma unroll
        for (int j = 0; j < 4; ++j)
            #pragma unroll
            for (int r = 0; r < 4; ++r) {
                int row = m0 + wm + i * 16 + quad * 4 + r;
                int col = n0 + wn + j * 16 + l15;
                Cg[(size_t)row * N + col] = acc[i][j][r];
            }
}

// ---------- MFMA flash attention: K LDS-staged, V direct-from-global ----------
// R13: wave-level subtile skip (bit-exact, barrier-safe).
// R16: V^T read per-lane 16B from global (L2-resident) — no V staging.
__global__ __launch_bounds__(256, 3)
void attn_kernel(const float* __restrict__ C, const unsigned short* __restrict__ Kh,
                 const unsigned short* __restrict__ Vt,
                 const unsigned int* __restrict__ maskbuf,
                 unsigned short* __restrict__ Og) {
    __shared__ unsigned short qv[8704];   // Q [64][132]
    __shared__ unsigned short k_s[8448];  // K [64][132]; output staging at end
    __shared__ unsigned short p_s[4352];  // P [64][68]
    __shared__ int kb_list[32];
    __shared__ int nsub_s;
    __shared__ unsigned int umask;

    int bid = blockIdx.x;
    int qt = 31 - (bid >> 5);             // longest-work-first
    int bh = bid & 31;
    int h = bh & 15, b = bh >> 4;
    int t = threadIdx.x;
    int wave = t >> 6, lane = t & 63;
    int quad = lane >> 4, l15 = lane & 15;
    int w16 = wave * 16;
    int q0 = qt * 64, qc = q0 >> 8, kvh = h >> 2;
    const float NEGINF = -__builtin_inff();

    #pragma unroll
    for (int it = 0; it < 8; ++it) {
        int idx = t + it * 256;
        int r = idx >> 5, c = (idx & 31) * 4;
        float4 v4 = *(const float4*)&C[(size_t)(b * 2048 + q0 + r) * 3072 + h * 128 + c];
        ushort4 u; u.x = f2h(v4.x); u.y = f2h(v4.y); u.z = f2h(v4.z); u.w = f2h(v4.w);
        *(ushort4*)&qv[r * 132 + c] = u;
    }
    if (t == 0) umask = 0;
    int mbase = ((b * 16 + h) << 11) + q0;
    unsigned int am[4];
    #pragma unroll
    for (int r = 0; r < 4; ++r)
        am[r] = maskbuf[mbase + w16 + quad * 4 + r];
    // wave-union mask: OR over this wave's 16 rows (2 shuffles across quads)
    unsigned int wam = am[0] | am[1] | am[2] | am[3];
    wam |= __shfl_xor((int)wam, 16);
    wam |= __shfl_xor((int)wam, 32);
    __syncthreads();
    if (t < 64) atomicOr(&umask, maskbuf[mbase + t]);
    f16x8 aq[4];
    #pragma unroll
    for (int ks = 0; ks < 4; ++ks)
        aq[ks] = *(const f16x8*)&qv[(w16 + l15) * 132 + ks * 32 + quad * 8];
    __syncthreads();
    if (t == 0) {
        unsigned int um = umask;
        int n = 0;
        for (int c = 0; c <= qc; ++c) {
            if (!((um >> c) & 1)) continue;
            int submax = (c == qc) ? ((q0 & 255) >> 6) : 3;
            for (int sub = 0; sub <= submax; ++sub) kb_list[n++] = c * 256 + sub * 64;
        }
        nsub_s = n;
    }
    __syncthreads();
    int nsub = nsub_s;

    float m_i[4], l_i[4];
    f32x4 o_acc[8];
    #pragma unroll
    for (int r = 0; r < 4; ++r) { m_i[r] = NEGINF; l_i[r] = 0.f; }
    #pragma unroll
    for (int n = 0; n < 8; ++n) o_acc[n] = (f32x4){0.f, 0.f, 0.f, 0.f};
    const float scale = 0.08838834764831845f;
    const unsigned short* Kb = Kh + (size_t)(b * 4 + kvh) * 2048 * 128;
    const unsigned short* Vb = Vt + (size_t)(b * 4 + kvh) * 128 * 2048;

    int kr = t >> 5, kc = (t & 31) * 4;

    ushort4 kpre[8];
    {
        int kb0 = kb_list[0];
        #pragma unroll
        for (int it = 0; it < 8; ++it)
            kpre[it] = *(const ushort4*)&Kb[(size_t)(kb0 + kr + it * 8) * 128 + kc];
    }

    for (int i = 0; i < nsub; ++i) {
        int kbase = kb_list[i];
        __syncthreads();
        #pragma unroll
        for (int it = 0; it < 8; ++it)
            *(ushort4*)&k_s[(kr + it * 8) * 132 + kc] = kpre[it];
        __syncthreads();
        if (i + 1 < nsub) {
            int kbn = kb_list[i + 1];
            #pragma unroll
            for (int it = 0; it < 8; ++it)
                kpre[it] = *(const ushort4*)&Kb[(size_t)(kbn + kr + it * 8) * 128 + kc];
        }
        // wave-level skip: contribution provably zero (wave-uniform branch)
        bool wskip = !((wam >> (kbase >> 8)) & 1) || (kbase > q0 + w16 + 15);
        if (wskip) continue;
        f32x4 s[4];
        #pragma unroll
        for (int j = 0; j < 4; ++j) {
            f32x4 sj = {0.f, 0.f, 0.f, 0.f};
            #pragma unroll
            for (int ks = 0; ks < 4; ++ks) {
                f16x8 bf = *(const f16x8*)&k_s[(j * 16 + l15) * 132 + ks * 32 + quad * 8];
                sj = __builtin_amdgcn_mfma_f32_16x16x32_f16(aq[ks], bf, sj, 0, 0, 0);
            }
            s[j] = sj;
        }
        #pragma unroll
        for (int r = 0; r < 4; ++r) {
            int qpos = q0 + w16 + quad * 4 + r;
            bool allow = (am[r] >> (kbase >> 8)) & 1;
            float sv[4], rmax = NEGINF;
            #pragma unroll
            for (int j = 0; j < 4; ++j) {
                int kpos = kbase + j * 16 + l15;
                float x = s[j][r] * scale;
                if (!allow || kpos > qpos) x = NEGINF;
                sv[j] = x;
                rmax = fmaxf(rmax, x);
            }
            // 16-lane DPP butterfly max (replaces 4 ds_swizzle shfl_xor steps)
            rmax = fmaxf(rmax, DPPF(rmax, 0xB1));
            rmax = fmaxf(rmax, DPPF(rmax, 0x4E));
            rmax = fmaxf(rmax, DPPF(rmax, 0x141));
            rmax = fmaxf(rmax, DPPF(rmax, 0x128));
            float mnew = fmaxf(m_i[r], rmax);
            float alpha = (m_i[r] == NEGINF) ? 0.f : __expf(m_i[r] - mnew);
            float ps[4], lsum = 0.f;
            #pragma unroll
            for (int j = 0; j < 4; ++j) {
                float p = (sv[j] == NEGINF) ? 0.f : __expf(sv[j] - mnew);
                ps[j] = p; lsum += p;
            }
            // 16-lane DPP butterfly sum
            lsum += DPPF(lsum, 0xB1);
            lsum += DPPF(lsum, 0x4E);
            lsum += DPPF(lsum, 0x141);
            lsum += DPPF(lsum, 0x128);
            l_i[r] = l_i[r] * alpha + lsum;
            m_i[r] = mnew;
            #pragma unroll
            for (int n = 0; n < 8; ++n) o_acc[n][r] *= alpha;
            #pragma unroll
            for (int j = 0; j < 4; ++j)
                p_s[(w16 + quad * 4 + r) * 68 + j * 16 + l15] = f2h(ps[j]);
        }
        f16x8 pa0 = *(const f16x8*)&p_s[(w16 + l15) * 68 + quad * 8];
        f16x8 pa1 = *(const f16x8*)&p_s[(w16 + l15) * 68 + 32 + quad * 8];
        // PV: V^T fragments direct from global (per-lane 16B, L2-resident)
        #pragma unroll
        for (int n = 0; n < 8; ++n) {
            f16x8 b0 = *(const f16x8*)&Vb[(size_t)(n * 16 + l15) * 2048 + kbase + quad * 8];
            f16x8 b1 = *(const f16x8*)&Vb[(size_t)(n * 16 + l15) * 2048 + kbase + 32 + quad * 8];
            o_acc[n] = __builtin_amdgcn_mfma_f32_16x16x32_f16(pa0, b0, o_acc[n], 0, 0, 0);
            o_acc[n] = __builtin_amdgcn_mfma_f32_16x16x32_f16(pa1, b1, o_acc[n], 0, 0, 0);
        }
    }
    __syncthreads();
    #pragma unroll
    for (int r = 0; r < 4; ++r) {
        float inv = (l_i[r] > 0.f) ? 1.f / l_i[r] : 0.f;
        #pragma unroll
        for (int n = 0; n < 8; ++n)
            k_s[(w16 + quad * 4 + r) * 132 + n * 16 + l15] = f2h(o_acc[n][r] * inv);
    }
    __syncthreads();
    #pragma unroll
    for (int it = 0; it < 8; ++it) {
        int idx = t + it * 256;
        int r = idx >> 5, cpos = (idx & 31) * 4;
        *(ushort4*)&Og[(size_t)(b * 2048 + q0 + r) * 2048 + h * 128 + cpos] =
            *(ushort4*)&k_s[r * 132 + cpos];
    }
}

// ---------- launch ----------
extern "C" void kernel_launch(void* const* d_in, const int* in_sizes, int n_in,
                              void* d_out, int out_size, void* d_ws, size_t ws_size,
                              hipStream_t stream) {
    const float* hs = (const float*)d_in[0];
    const float* wq = (const float*)d_in[1];
    const float* wk = (const float*)d_in[2];
    const float* wv = (const float*)d_in[3];
    const float* wo = (const float*)d_in[4];
    float* out = (float*)d_out;
    char* ws = (char*)d_ws;

    // phase-1 (gate) buffers, overlapped with the Cqkv region:
    double*         Act  = (double*)       (ws + 37748736);    // 16.78 MB
    double*         Ast  = (double*)       (ws + 54525952);    // 16.78 MB
    // phase-2 buffers:
    unsigned short* hsh  = (unsigned short*)(ws + 0);          // 16.78 MB
    unsigned short* Wth  = (unsigned short*)(ws + 16777216);   // 12.58 MB
    unsigned short* woth = (unsigned short*)(ws + 29360128);   //  8.39 MB
    float*          Cqkv = (float*)        (ws + 37748736);    // 50.33 MB
    unsigned short* Og   = (unsigned short*)(ws + 88080384);   // 16.78 MB
    // persistent:
    double*         km64 = (double*)       (ws + 104857600);   // 64 KB
    unsigned int*   mskb = (unsigned int*) (ws + 104923136);   // 512 KB
    float*          ct   = (float*)        (ws + 105447424);   // 512 KB
    float*          st   = (float*)        (ws + 105971712);   // 512 KB
    unsigned short* Kh   = (unsigned short*)(ws + 106496000);  //  8.39 MB
    unsigned short* Vt   = (unsigned short*)(ws + 114884608);  //  8.39 MB
    int*            fcnt = (int*)          (ws + 123273216);   // 64 B (16 ints)
    int*            flst = (int*)          (ws + 123273280);   // 256 KB (16 x 4096)

    fused0_kernel <<<18944, 256, 0, stream>>>(ct, st, km64, fcnt, hs, hsh,
                                              wq, wk, wv, wo, Wth, woth);
    ksum_kernel   <<<dim3(32, 16), 256, 0, stream>>>(hs, ct, st, Act, Ast);
    kmeanw_kernel <<<2048, 256, 0, stream>>>(Act, Ast, wk, km64);
    gemm_kernel   <<<dim3(24, 32), 256, 0, stream>>>(hsh, Wth, Cqkv, 4096, 3072, 2048);
    ropegate_kernel<<<4096, 256, 0, stream>>>(Cqkv, ct, st, km64, mskb, fcnt, flst);
    fusedrk_kernel<<<4352, 256, 0, stream>>>(hs, wq, ct, st, km64, fcnt, flst, mskb,
                                             Cqkv, Kh, Vt);
    attn_kernel   <<<1024, 256, 0, stream>>>(Cqkv, Kh, Vt, mskb, Og);
    gemm_kernel   <<<dim3(16, 32), 256, 0, stream>>>(Og, woth, out, 4096, 2048, 2048);
}

// Round 19
// 559.083 us; speedup vs baseline: 1.1233x; 1.1233x over previous
//
#include <hip/hip_runtime.h>
#include <stdint.h>
#include <math.h>

// ---------- types / helpers ----------
typedef _Float16 f16x8 __attribute__((ext_vector_type(8)));
typedef float    f32x4 __attribute__((ext_vector_type(4)));
typedef __attribute__((address_space(1))) void as1_void;
typedef __attribute__((address_space(3))) void as3_void;

__device__ __forceinline__ unsigned short f2h(float x) {
    _Float16 h = (_Float16)x;
    return __builtin_bit_cast(unsigned short, h);
}
__device__ __forceinline__ float h2f(unsigned short u) {
    return (float)__builtin_bit_cast(_Float16, u);
}
// async global->LDS, 16B/lane; lds dest must be wave-uniform base (HW adds lane*16)
__device__ __forceinline__ void glds16(const void* g, void* l) {
    __builtin_amdgcn_global_load_lds((as1_void*)g, (as3_void*)l, 16, 0, 0);
}

// 16-lane DPP butterfly step (VALU-speed, avoids ds_swizzle latency of __shfl_xor):
// 0xB1 = quad_perm(1,0,3,2) ~ xor1 ; 0x4E = quad_perm(2,3,0,1) ~ xor2 ;
// 0x141 = row_half_mirror (pairs across quads within 8) ; 0x128 = row_ror:8 ~ xor8.
#define DPPF(v, ctrl) __builtin_bit_cast(float, \
    __builtin_amdgcn_update_dpp(0, __builtin_bit_cast(int, (v)), (ctrl), 0xF, 0xF, true))

// B=2, S=2048, Hid=2048, NH=16, NKV=4, D=128, chunks: 8 x 256, TOPK=4
//
// R17 lesson: V-direct-from-global regressed 105->183us (exposed L2 latency
// inside the PV MFMA chain; FETCH down but MfmaUtil halved). V prefetch->LDS
// restored: prefetch one subtile ahead hides latency; LDS is the layout
// shuffle medium. attn ~104us is this structure's verified local optimum.
// R15 fusions (bit-exact; 8 launches): fused0 = setup|split|packall,
// fusedrk = repair|kvprep.
// Gate strategy (margin-filtered repair):
//  - exact fp64 kmean via rope-factorization (ksum/kmeanw)
//  - provisional gates from fp16-MFMA q vs exact km64 (fused into ropegate;
//    8-lane-group reduce — R11); margin < TAU -> fp64 repair, h-bucketed
// Value path: fp16 MFMA QKV GEMM (global_load_lds staging), fused fp32
// rope+gates, fp16 MFMA flash attn (LDS-staged + register prefetch,
// DPP row-reduce softmax; 16 rows/wave = 3 blocks/CU; R13 wave-level
// subtile skip, bit-exact, barrier-safe), fp16 out-proj.
//
// VGPR discipline (R3+R10): live-VGPR must fit 512/(waves-per-EU bound);
// spill signature = WRITE_SIZE blowup + forced-low VGPR_Count.

#define TAU 0.015
#define FLAGCAP 4096

// ---------- fused0: setup | split | packall ----------
// grid: [0,512) setup ; [512,8704) split ; [8704,18944) packall
__global__ __launch_bounds__(256)
void fused0_kernel(float* __restrict__ ct, float* __restrict__ st,
                   double* __restrict__ km, int* __restrict__ flagcnt,
                   const float* __restrict__ hs, unsigned short* __restrict__ hsh,
                   const float* __restrict__ wq, const float* __restrict__ wk,
                   const float* __restrict__ wv, const float* __restrict__ wo,
                   unsigned short* __restrict__ Wh, unsigned short* __restrict__ Woh) {
    int bid = blockIdx.x;
    int t = threadIdx.x;
    if (bid < 512) {
        // ---- setup: CR-fp32 sincos tables + zero km64 + zero flag counters
        int gid = bid * 256 + t;            // 512*256 = 2048*64
        if (gid < 16) flagcnt[gid] = 0;
        if (gid < 8192) km[gid] = 0.0;
        int i = gid & 63, s = gid >> 6;
        float xf = (float)i * (1.0f / 64.0f);
        float pf = (float)pow(10000.0, (double)xf);     // CR fp32 pow
        float inv = 1.0f / pf;                          // second fp32 rounding (np)
        float ang = (float)s * inv;
        ct[gid] = (float)cos((double)ang);
        st[gid] = (float)sin((double)ang);
    } else if (bid < 8704) {
        // ---- split: hs fp32 -> fp16 (2097152 float4 groups)
        int i = (bid - 512) * 256 + t;
        if (i >= 2097152) return;
        float4 v = ((const float4*)hs)[i];
        ushort4 h;
        h.x = f2h(v.x); h.y = f2h(v.y); h.z = f2h(v.z); h.w = f2h(v.w);
        ((ushort4*)hsh)[i] = h;
    } else {
        // ---- packall: [wq|wk|wv]^T -> Wh[n][k], wo^T -> Woh[n][k], fp16
        int gid = (bid - 8704) * 256 + t;
        if (gid < 3072 * 512) {
            int n  = gid % 3072;
            int kg = gid / 3072;
            const float* src; int ldn, col;
            if (n < 2048)      { src = wq; ldn = 2048; col = n; }
            else if (n < 2560) { src = wk; ldn = 512;  col = n - 2048; }
            else               { src = wv; ldn = 512;  col = n - 2560; }
            int k0 = kg * 4;
            ushort4 h;
            h.x = f2h(src[(size_t)(k0 + 0) * ldn + col]);
            h.y = f2h(src[(size_t)(k0 + 1) * ldn + col]);
            h.z = f2h(src[(size_t)(k0 + 2) * ldn + col]);
            h.w = f2h(src[(size_t)(k0 + 3) * ldn + col]);
            *(ushort4*)&Wh[(size_t)n * 2048 + k0] = h;
        } else {
            int g2 = gid - 3072 * 512;   // 2048*512
            int n  = g2 % 2048;
            int kg = g2 / 2048;
            int k0 = kg * 4;
            ushort4 h;
            h.x = f2h(wo[(size_t)(k0 + 0) * 2048 + n]);
            h.y = f2h(wo[(size_t)(k0 + 1) * 2048 + n]);
            h.z = f2h(wo[(size_t)(k0 + 2) * 2048 + n]);
            h.w = f2h(wo[(size_t)(k0 + 3) * 2048 + n]);
            *(ushort4*)&Woh[(size_t)n * 2048 + k0] = h;
        }
    }
}

// ---------- trig-weighted chunk sums: Act/Ast[bn][h][d] (fp64) ----------
__global__ __launch_bounds__(256)
void ksum_kernel(const float* __restrict__ hs, const float* __restrict__ ct,
                 const float* __restrict__ st, double* __restrict__ Act,
                 double* __restrict__ Ast) {
    __shared__ float Hs[16][68];
    __shared__ float Tc[16][68];
    __shared__ float Ts[16][68];
    int bn = blockIdx.y;             // b*8 + n
    int h0 = blockIdx.x * 64;
    int b = bn >> 3, n = bn & 7;
    int t = threadIdx.x;
    int tx = t & 15, ty = t >> 4;
    int d0 = tx * 4, hl0 = ty * 4;
    int si = t & 15, g4 = (t >> 4) * 4;
    double ac[4][4] = {}, as_[4][4] = {};
    for (int s0 = 0; s0 < 256; s0 += 16) {
        __syncthreads();
        int srow = n * 256 + s0 + si;
        *(float4*)&Hs[si][g4] = *(const float4*)&hs[(size_t)(b * 2048 + srow) * 2048 + h0 + g4];
        *(float4*)&Tc[si][g4] = *(const float4*)&ct[srow * 64 + g4];
        *(float4*)&Ts[si][g4] = *(const float4*)&st[srow * 64 + g4];
        __syncthreads();
        #pragma unroll
        for (int kk = 0; kk < 16; ++kk) {
            double hv[4], cv[4], sv[4];
            #pragma unroll
            for (int j = 0; j < 4; ++j) hv[j] = (double)Hs[kk][hl0 + j];
            #pragma unroll
            for (int i = 0; i < 4; ++i) { cv[i] = (double)Tc[kk][d0 + i]; sv[i] = (double)Ts[kk][d0 + i]; }
            #pragma unroll
            for (int i = 0; i < 4; ++i)
                #pragma unroll
                for (int j = 0; j < 4; ++j) {
                    ac[i][j]  = fma(cv[i], hv[j], ac[i][j]);
                    as_[i][j] = fma(sv[i], hv[j], as_[i][j]);
                }
        }
    }
    #pragma unroll
    for (int j = 0; j < 4; ++j) {
        size_t rb = ((size_t)bn * 2048 + h0 + hl0 + j) * 64 + d0;
        double2 c0 = {ac[0][j], ac[1][j]},  c1 = {ac[2][j], ac[3][j]};
        double2 s0_ = {as_[0][j], as_[1][j]}, s1_ = {as_[2][j], as_[3][j]};
        *(double2*)&Act[rb] = c0; *(double2*)&Act[rb + 2] = c1;
        *(double2*)&Ast[rb] = s0_; *(double2*)&Ast[rb + 2] = s1_;
    }
}

// ---------- contract Act/Ast with wk -> exact km64 ----------
__global__ __launch_bounds__(256)
void kmeanw_kernel(const double* __restrict__ Act, const double* __restrict__ Ast,
                   const float* __restrict__ wk, double* __restrict__ km) {
    __shared__ double red[256];
    int blk = blockIdx.x;            // ((bn*4 + kvh)*32 + hp)
    int hp = blk & 31, kvh = (blk >> 5) & 3, bn = blk >> 7;
    int t = threadIdx.x;
    int d = t & 127, sub = t >> 7;
    int jj = d & 63;
    int col1 = kvh * 128 + d;
    int col2 = kvh * 128 + (d ^ 64);
    double sgn = (d < 64) ? -1.0 : 1.0;
    const double* actb = Act + (size_t)bn * 2048 * 64;
    const double* astb = Ast + (size_t)bn * 2048 * 64;
    double a1 = 0.0, a2 = 0.0, b1 = 0.0, b2 = 0.0;
    double c1 = 0.0, c2 = 0.0, d1 = 0.0, d2 = 0.0;
    int hbeg = hp * 64 + sub * 32;   // 32 hp x 64 + 2 sub x 32 covers [0,2048)
    #pragma unroll 2
    for (int h = hbeg; h < hbeg + 32; h += 4) {
        a1 = fma(actb[(size_t)(h + 0) * 64 + jj], (double)wk[(size_t)(h + 0) * 512 + col1], a1);
        a2 = fma(astb[(size_t)(h + 0) * 64 + jj], (double)wk[(size_t)(h + 0) * 512 + col2], a2);
        b1 = fma(actb[(size_t)(h + 1) * 64 + jj], (double)wk[(size_t)(h + 1) * 512 + col1], b1);
        b2 = fma(astb[(size_t)(h + 1) * 64 + jj], (double)wk[(size_t)(h + 1) * 512 + col2], b2);
        c1 = fma(actb[(size_t)(h + 2) * 64 + jj], (double)wk[(size_t)(h + 2) * 512 + col1], c1);
        c2 = fma(astb[(size_t)(h + 2) * 64 + jj], (double)wk[(size_t)(h + 2) * 512 + col2], c2);
        d1 = fma(actb[(size_t)(h + 3) * 64 + jj], (double)wk[(size_t)(h + 3) * 512 + col1], d1);
        d2 = fma(astb[(size_t)(h + 3) * 64 + jj], (double)wk[(size_t)(h + 3) * 512 + col2], d2);
    }
    double acc1 = (a1 + b1) + (c1 + d1);
    double acc2 = (a2 + b2) + (c2 + d2);
    red[t] = acc1 + sgn * acc2;
    __syncthreads();
    if (t < 128) {
        double v = red[t] + red[t + 128];
        atomicAdd(&km[((size_t)bn * 4 + kvh) * 128 + d], v * (1.0 / 256.0));
    }
}

// ---------- fused rope (q,k in-place) + provisional fp64 gates + margin flags ----
// R11: 8-lane-group-per-chunk reduce, 3-step butterfly + 8 gathers.
__global__ __launch_bounds__(256)
void ropegate_kernel(float* __restrict__ C, const float* __restrict__ ct,
                     const float* __restrict__ st, const double* __restrict__ km,
                     unsigned int* __restrict__ maskbuf,
                     int* __restrict__ flagcnt, int* __restrict__ flaglist) {
    __shared__ float qbuf[2048];
    int bs = blockIdx.x;             // b*2048 + s
    int s = bs & 2047, b = bs >> 11;
    int t = threadIdx.x;
    size_t base = (size_t)bs * 3072;
    #pragma unroll
    for (int it = 0; it < 5; ++it) {  // 20 heads x 64 pairs = 1280 = 5*256
        int p = t + it * 256;
        int hd = p >> 6, i = p & 63;
        float cs = ct[s * 64 + i], sn = st[s * 64 + i];
        float x1 = C[base + hd * 128 + i];
        float x2 = C[base + hd * 128 + i + 64];
        float n1 = x1 * cs - x2 * sn;
        float n2 = x2 * cs + x1 * sn;
        C[base + hd * 128 + i] = n1;
        C[base + hd * 128 + i + 64] = n2;
        if (hd < 16) { qbuf[hd * 128 + i] = n1; qbuf[hd * 128 + i + 64] = n2; }
    }
    __syncthreads();
    int wave = t >> 6, lane = t & 63;
    int grp = lane >> 3, j = lane & 7;   // group -> chunk n, j -> d sub-lane
    int qc = s >> 8;
    const double INF = __builtin_inf();
    #pragma unroll
    for (int ii = 0; ii < 4; ++ii) {
        int h = wave * 4 + ii;
        int kvh = h >> 2;
        size_t kb = (size_t)((b * 8 + grp) * 4 + kvh) * 128;
        const float* qh = qbuf + h * 128;
        double acc0 = 0.0, acc1 = 0.0;
        #pragma unroll
        for (int i = 0; i < 8; ++i) {
            int d = j + 8 * i;
            acc0 = fma((double)qh[d],      km[kb + d],      acc0);
            acc1 = fma((double)qh[d + 64], km[kb + 64 + d], acc1);
        }
        double acc = acc0 + acc1;
        // 3-step butterfly within the 8-lane group (chunk-local sum)
        acc += __shfl_xor(acc, 1);
        acc += __shfl_xor(acc, 2);
        acc += __shfl_xor(acc, 4);
        // gather group sums: g[n] lives in lanes n*8..n*8+7
        double g[8];
        #pragma unroll
        for (int n = 0; n < 8; ++n) g[n] = __shfl(acc, n * 8);
        #pragma unroll
        for (int n = 0; n < 8; ++n) {
            if (n == qc)                g[n] = INF;
            else if (s < (n + 1) * 256) g[n] = -INF;
        }
        unsigned int msk = 0;
        for (int p = 0; p < 4; ++p) {  // iterative argmax; strict > => lowest idx on ties
            double best = -INF; int bi = -1;
            #pragma unroll
            for (int n = 0; n < 8; ++n)
                if (!((msk >> n) & 1) && g[n] > best) { best = g[n]; bi = n; }
            if (bi >= 0) msk |= 1u << bi;
        }
        if (lane == 0) {
            int wid = ((b * 16 + h) << 11) + s;
            maskbuf[wid] = msk;
            if (qc >= 4) {
                double worst_in = INF, best_out = -INF;
                #pragma unroll
                for (int n = 0; n < 8; ++n) {
                    if ((msk >> n) & 1) worst_in = fmin(worst_in, g[n]);
                    else if (g[n] > -1e300) best_out = fmax(best_out, g[n]);
                }
                if (worst_in - best_out < TAU) {
                    int ix = atomicAdd(&flagcnt[h], 1);
                    if (ix < FLAGCAP) flaglist[h * FLAGCAP + ix] = wid;
                }
            }
        }
    }
}

// ---------- fusedrk: repair (h-bucketed) | kvprep ----------
// grid: [0,4096) repair ; [4096,4352) kvprep. LDS union = 25856B (repair's
// footprint) -> repair occupancy unchanged; kvprep's 18432B fits inside.
__global__ __launch_bounds__(256)
void fusedrk_kernel(const float* __restrict__ hs, const float* __restrict__ wq,
                    const float* __restrict__ ct, const float* __restrict__ st,
                    const double* __restrict__ km, const int* __restrict__ flagcnt,
                    const int* __restrict__ flaglist, unsigned int* __restrict__ maskbuf,
                    const float* __restrict__ C, unsigned short* __restrict__ Kh,
                    unsigned short* __restrict__ Vt) {
    __shared__ char SH[25856];
    int t = threadIdx.x;
    if (blockIdx.x < 4096) {
        // ---- repair path (R5 ILP + R6 h-bucketing)
        double* hrow_d = (double*)SH;                       // 2048 d = 16384B
        double (*red)[132] = (double(*)[132])(SH + 16384);  // 8x132 d = 8448B
        double* qs = (double*)(SH + 24832);                 // 128 d = 1024B
        int hb = blockIdx.x >> 8;         // 16 head groups x 256 blocks
        int nflag = flagcnt[hb];
        if (nflag > FLAGCAP) nflag = FLAGCAP;
        const int* list = flaglist + hb * FLAGCAP;
        int dg = t & 31, sub = t >> 5;    // d = dg*4..+3 ; k in [sub*256, +256)
        for (int idx = blockIdx.x & 255; idx < nflag; idx += 256) {
            int wid = list[idx];
            int s = wid & 2047;
            int h = (wid >> 11) & 15;
            int b = wid >> 15;
            int kvh = h >> 2;
            __syncthreads();
            {   // cooperative coalesced fp32->fp64 row stage
                const float4* src = (const float4*)(hs + (size_t)(b * 2048 + s) * 2048);
                float4 v0 = src[t], v1 = src[t + 256];
                hrow_d[4 * t + 0] = (double)v0.x; hrow_d[4 * t + 1] = (double)v0.y;
                hrow_d[4 * t + 2] = (double)v0.z; hrow_d[4 * t + 3] = (double)v0.w;
                hrow_d[4 * t + 1024 + 0] = (double)v1.x; hrow_d[4 * t + 1024 + 1] = (double)v1.y;
                hrow_d[4 * t + 1024 + 2] = (double)v1.z; hrow_d[4 * t + 1024 + 3] = (double)v1.w;
            }
            __syncthreads();
            const float* wbase = wq + (size_t)(sub * 256) * 2048 + h * 128 + dg * 4;
            const double* hb_ = hrow_d + sub * 256;
            double a0 = 0, a1 = 0, a2 = 0, a3 = 0;
            double c0 = 0, c1 = 0, c2 = 0, c3 = 0;
            #pragma unroll 4
            for (int k = 0; k < 256; k += 2) {
                float4 w0 = *(const float4*)&wbase[(size_t)k * 2048];
                float4 w1 = *(const float4*)&wbase[(size_t)(k + 1) * 2048];
                double h0 = hb_[k], h1 = hb_[k + 1];
                a0 = fma(h0, (double)w0.x, a0); a1 = fma(h0, (double)w0.y, a1);
                a2 = fma(h0, (double)w0.z, a2); a3 = fma(h0, (double)w0.w, a3);
                c0 = fma(h1, (double)w1.x, c0); c1 = fma(h1, (double)w1.y, c1);
                c2 = fma(h1, (double)w1.z, c2); c3 = fma(h1, (double)w1.w, c3);
            }
            red[sub][dg * 4 + 0] = a0 + c0; red[sub][dg * 4 + 1] = a1 + c1;
            red[sub][dg * 4 + 2] = a2 + c2; red[sub][dg * 4 + 3] = a3 + c3;
            __syncthreads();
            if (t < 128) {
                double v = 0.0;
                #pragma unroll
                for (int u = 0; u < 8; ++u) v += red[u][t];
                qs[t] = v;
            }
            __syncthreads();
            if (t < 64) {
                double c  = (double)ct[s * 64 + t];
                double sn = (double)st[s * 64 + t];
                double x1 = qs[t], x2 = qs[t + 64];
                qs[t]      = x1 * c - x2 * sn;
                qs[t + 64] = x2 * c + x1 * sn;
            }
            __syncthreads();
            if (t < 64) {
                double g[8];
                #pragma unroll
                for (int n = 0; n < 8; ++n) {
                    size_t kb = (size_t)((b * 8 + n) * 4 + kvh) * 128;
                    double v = qs[t] * km[kb + t] + qs[t + 64] * km[kb + 64 + t];
                    #pragma unroll
                    for (int off = 32; off; off >>= 1) v += __shfl_xor(v, off);
                    g[n] = v;
                }
                int qc = s >> 8;
                const double INF = __builtin_inf();
                #pragma unroll
                for (int n = 0; n < 8; ++n) {
                    if (n == qc)                g[n] = INF;
                    else if (s < (n + 1) * 256) g[n] = -INF;
                }
                unsigned int msk = 0;
                for (int p = 0; p < 4; ++p) {
                    double best = -INF; int bi = -1;
                    #pragma unroll
                    for (int n = 0; n < 8; ++n)
                        if (!((msk >> n) & 1) && g[n] > best) { best = g[n]; bi = n; }
                    if (bi >= 0) msk |= 1u << bi;
                }
                if (t == 0) maskbuf[wid] = msk;
            }
            __syncthreads();
        }
    } else {
        // ---- kvprep path: K -> fp16 row-major, V -> fp16 transposed
        unsigned short (*vt)[72] = (unsigned short(*)[72])SH;   // 128x72 us = 18432B
        int blk = blockIdx.x - 4096;   // (b*4+kvh)*32 + kt
        int kt = blk & 31, kvh = (blk >> 5) & 3, b = blk >> 7;
        int key0 = kt * 64;
        #pragma unroll
        for (int it = 0; it < 8; ++it) {
            int idx = t + it * 256;
            int r = idx >> 5, c = (idx & 31) * 4;
            size_t rowb = (size_t)(b * 2048 + key0 + r) * 3072;
            float4 kv = *(const float4*)&C[rowb + 2048 + kvh * 128 + c];
            ushort4 u; u.x = f2h(kv.x); u.y = f2h(kv.y); u.z = f2h(kv.z); u.w = f2h(kv.w);
            *(ushort4*)&Kh[((size_t)(b * 4 + kvh) * 2048 + key0 + r) * 128 + c] = u;
            float4 vv = *(const float4*)&C[rowb + 2560 + kvh * 128 + c];
            vt[c + 0][r] = f2h(vv.x); vt[c + 1][r] = f2h(vv.y);
            vt[c + 2][r] = f2h(vv.z); vt[c + 3][r] = f2h(vv.w);
        }
        __syncthreads();
        #pragma unroll
        for (int it = 0; it < 8; ++it) {
            int idx = t + it * 256;
            int d = idx >> 4, c4 = (idx & 15) * 4;
            *(ushort4*)&Vt[((size_t)(b * 4 + kvh) * 128 + d) * 2048 + key0 + c4] =
                *(ushort4*)&vt[d][c4];
        }
    }
}

// ---------- fp16 MFMA GEMM, m97-style global_load_lds staging ----------
// A row-major [m][k]; B pre-transposed [n][k]; unpadded LDS tiles [128][32].
__global__ __launch_bounds__(256, 2)
void gemm_kernel(const unsigned short* __restrict__ A_g, const unsigned short* __restrict__ B_g,
                 float* __restrict__ Cg, int M, int N, int K) {
    __shared__ unsigned short Ah[128 * 32];
    __shared__ unsigned short Bh[128 * 32];
    int n0 = blockIdx.x * 128, m0 = blockIdx.y * 128;
    int t = threadIdx.x;
    int wave = t >> 6, lane = t & 63;
    int quad = lane >> 4, l15 = lane & 15;
    int wm = (wave >> 1) * 64, wn = (wave & 1) * 64;

    f32x4 acc[4][4];
    f32x4 zero = {0.f, 0.f, 0.f, 0.f};
    for (int i = 0; i < 4; ++i)
        for (int j = 0; j < 4; ++j) acc[i][j] = zero;

    // staging: lane covers row (lane>>2), 8 halves at col (lane&3)*8 of a 16-row segment
    int srow = lane >> 2, scol = (lane & 3) * 8;
    const unsigned short* Ag0 = &A_g[(size_t)(m0 + wave * 16 + srow) * K + scol];
    const unsigned short* Ag1 = &A_g[(size_t)(m0 + 64 + wave * 16 + srow) * K + scol];
    const unsigned short* Bg0 = &B_g[(size_t)(n0 + wave * 16 + srow) * K + scol];
    const unsigned short* Bg1 = &B_g[(size_t)(n0 + 64 + wave * 16 + srow) * K + scol];
    unsigned short* Al0 = &Ah[(wave * 16) * 32];
    unsigned short* Al1 = &Ah[(64 + wave * 16) * 32];
    unsigned short* Bl0 = &Bh[(wave * 16) * 32];
    unsigned short* Bl1 = &Bh[(64 + wave * 16) * 32];

    for (int k0 = 0; k0 < K; k0 += 32) {
        __syncthreads();
        glds16(Ag0 + k0, Al0);
        glds16(Ag1 + k0, Al1);
        glds16(Bg0 + k0, Bl0);
        glds16(Bg1 + k0, Bl1);
        __syncthreads();   // drains vmcnt -> staging visible
        f16x8 ah[4], bh[4];
        #pragma unroll
        for (int i = 0; i < 4; ++i) {
            ah[i] = *(const f16x8*)&Ah[(wm + i * 16 + l15) * 32 + quad * 8];
            bh[i] = *(const f16x8*)&Bh[(wn + i * 16 + l15) * 32 + quad * 8];
        }
        #pragma unroll
        for (int i = 0; i < 4; ++i)
            #pragma unroll
            for (int j = 0; j < 4; ++j)
                acc[i][j] = __builtin_amdgcn_mfma_f32_16x16x32_f16(ah[i], bh[j], acc[i][j], 0, 0, 0);
    }
    #pragma unroll
    for (int i = 0; i < 4; ++i)
        #pragma unroll
        for (int j = 0; j < 4; ++j)
            #pragma unroll
            for (int r = 0; r < 4; ++r) {
                int row = m0 + wm + i * 16 + quad * 4 + r;
                int col = n0 + wn + j * 16 + l15;
                Cg[(size_t)row * N + col] = acc[i][j][r];
            }
}

// ---------- MFMA flash attention: LDS-staged, register-prefetch pipelined ----------
// R13: wave-level subtile skip (bit-exact, barrier-safe).
__global__ __launch_bounds__(256, 3)
void attn_kernel(const float* __restrict__ C, const unsigned short* __restrict__ Kh,
                 const unsigned short* __restrict__ Vt,
                 const unsigned int* __restrict__ maskbuf,
                 unsigned short* __restrict__ Og) {
    __shared__ unsigned short qv[8704];   // Q [64][132] -> V^T [128][68]
    __shared__ unsigned short k_s[8448];  // K [64][132]; output staging at end
    __shared__ unsigned short p_s[4352];  // P [64][68]
    __shared__ int kb_list[32];
    __shared__ int nsub_s;
    __shared__ unsigned int umask;

    int bid = blockIdx.x;
    int qt = 31 - (bid >> 5);             // longest-work-first
    int bh = bid & 31;
    int h = bh & 15, b = bh >> 4;
    int t = threadIdx.x;
    int wave = t >> 6, lane = t & 63;
    int quad = lane >> 4, l15 = lane & 15;
    int w16 = wave * 16;
    int q0 = qt * 64, qc = q0 >> 8, kvh = h >> 2;
    const float NEGINF = -__builtin_inff();

    #pragma unroll
    for (int it = 0; it < 8; ++it) {
        int idx = t + it * 256;
        int r = idx >> 5, c = (idx & 31) * 4;
        float4 v4 = *(const float4*)&C[(size_t)(b * 2048 + q0 + r) * 3072 + h * 128 + c];
        ushort4 u; u.x = f2h(v4.x); u.y = f2h(v4.y); u.z = f2h(v4.z); u.w = f2h(v4.w);
        *(ushort4*)&qv[r * 132 + c] = u;
    }
    if (t == 0) umask = 0;
    int mbase = ((b * 16 + h) << 11) + q0;
    unsigned int am[4];
    #pragma unroll
    for (int r = 0; r < 4; ++r)
        am[r] = maskbuf[mbase + w16 + quad * 4 + r];
    // wave-union mask: OR over this wave's 16 rows (2 shuffles across quads)
    unsigned int wam = am[0] | am[1] | am[2] | am[3];
    wam |= __shfl_xor((int)wam, 16);
    wam |= __shfl_xor((int)wam, 32);
    __syncthreads();
    if (t < 64) atomicOr(&umask, maskbuf[mbase + t]);
    f16x8 aq[4];
    #pragma unroll
    for (int ks = 0; ks < 4; ++ks)
        aq[ks] = *(const f16x8*)&qv[(w16 + l15) * 132 + ks * 32 + quad * 8];
    __syncthreads();
    if (t == 0) {
        unsigned int um = umask;
        int n = 0;
        for (int c = 0; c <= qc; ++c) {
            if (!((um >> c) & 1)) continue;
            int submax = (c == qc) ? ((q0 & 255) >> 6) : 3;
            for (int sub = 0; sub <= submax; ++sub) kb_list[n++] = c * 256 + sub * 64;
        }
        nsub_s = n;
    }
    __syncthreads();
    int nsub = nsub_s;

    float m_i[4], l_i[4];
    f32x4 o_acc[8];
    #pragma unroll
    for (int r = 0; r < 4; ++r) { m_i[r] = NEGINF; l_i[r] = 0.f; }
    #pragma unroll
    for (int n = 0; n < 8; ++n) o_acc[n] = (f32x4){0.f, 0.f, 0.f, 0.f};
    const float scale = 0.08838834764831845f;
    const unsigned short* Kb = Kh + (size_t)(b * 4 + kvh) * 2048 * 128;
    const unsigned short* Vb = Vt + (size_t)(b * 4 + kvh) * 128 * 2048;

    int kr = t >> 5, kc = (t & 31) * 4;
    int vr = t >> 4, vc = (t & 15) * 4;

    ushort4 kpre[8], vpre[8];
    {
        int kb0 = kb_list[0];
        #pragma unroll
        for (int it = 0; it < 8; ++it) {
            kpre[it] = *(const ushort4*)&Kb[(size_t)(kb0 + kr + it * 8) * 128 + kc];
            vpre[it] = *(const ushort4*)&Vb[(size_t)(vr + it * 16) * 2048 + kb0 + vc];
        }
    }

    for (int i = 0; i < nsub; ++i) {
        int kbase = kb_list[i];
        __syncthreads();
        #pragma unroll
        for (int it = 0; it < 8; ++it) {
            *(ushort4*)&k_s[(kr + it * 8) * 132 + kc] = kpre[it];
            *(ushort4*)&qv[(vr + it * 16) * 68 + vc] = vpre[it];
        }
        __syncthreads();
        if (i + 1 < nsub) {
            int kbn = kb_list[i + 1];
            #pragma unroll
            for (int it = 0; it < 8; ++it) {
                kpre[it] = *(const ushort4*)&Kb[(size_t)(kbn + kr + it * 8) * 128 + kc];
                vpre[it] = *(const ushort4*)&Vb[(size_t)(vr + it * 16) * 2048 + kbn + vc];
            }
        }
        // wave-level skip: contribution provably zero (wave-uniform branch)
        bool wskip = !((wam >> (kbase >> 8)) & 1) || (kbase > q0 + w16 + 15);
        if (wskip) continue;
        f32x4 s[4];
        #pragma unroll
        for (int j = 0; j < 4; ++j) {
            f32x4 sj = {0.f, 0.f, 0.f, 0.f};
            #pragma unroll
            for (int ks = 0; ks < 4; ++ks) {
                f16x8 bf = *(const f16x8*)&k_s[(j * 16 + l15) * 132 + ks * 32 + quad * 8];
                sj = __builtin_amdgcn_mfma_f32_16x16x32_f16(aq[ks], bf, sj, 0, 0, 0);
            }
            s[j] = sj;
        }
        #pragma unroll
        for (int r = 0; r < 4; ++r) {
            int qpos = q0 + w16 + quad * 4 + r;
            bool allow = (am[r] >> (kbase >> 8)) & 1;
            float sv[4], rmax = NEGINF;
            #pragma unroll
            for (int j = 0; j < 4; ++j) {
                int kpos = kbase + j * 16 + l15;
                float x = s[j][r] * scale;
                if (!allow || kpos > qpos) x = NEGINF;
                sv[j] = x;
                rmax = fmaxf(rmax, x);
            }
            // 16-lane DPP butterfly max (replaces 4 ds_swizzle shfl_xor steps)
            rmax = fmaxf(rmax, DPPF(rmax, 0xB1));
            rmax = fmaxf(rmax, DPPF(rmax, 0x4E));
            rmax = fmaxf(rmax, DPPF(rmax, 0x141));
            rmax = fmaxf(rmax, DPPF(rmax, 0x128));
            float mnew = fmaxf(m_i[r], rmax);
            float alpha = (m_i[r] == NEGINF) ? 0.f : __expf(m_i[r] - mnew);
            float ps[4], lsum = 0.f;
            #pragma unroll
            for (int j = 0; j < 4; ++j) {
                float p = (sv[j] == NEGINF) ? 0.f : __expf(sv[j] - mnew);
                ps[j] = p; lsum += p;
            }
            // 16-lane DPP butterfly sum
            lsum += DPPF(lsum, 0xB1);
            lsum += DPPF(lsum, 0x4E);
            lsum += DPPF(lsum, 0x141);
            lsum += DPPF(lsum, 0x128);
            l_i[r] = l_i[r] * alpha + lsum;
            m_i[r] = mnew;
            #pragma unroll
            for (int n = 0; n < 8; ++n) o_acc[n][r] *= alpha;
            #pragma unroll
            for (int j = 0; j < 4; ++j)
                p_s[(w16 + quad * 4 + r) * 68 + j * 16 + l15] = f2h(ps[j]);
        }
        f16x8 pa0 = *(const f16x8*)&p_s[(w16 + l15) * 68 + quad * 8];
        f16x8 pa1 = *(const f16x8*)&p_s[(w16 + l15) * 68 + 32 + quad * 8];
        #pragma unroll
        for (int n = 0; n < 8; ++n) {
            f16x8 b0 = *(const f16x8*)&qv[(n * 16 + l15) * 68 + quad * 8];
            f16x8 b1 = *(const f16x8*)&qv[(n * 16 + l15) * 68 + 32 + quad * 8];
            o_acc[n] = __builtin_amdgcn_mfma_f32_16x16x32_f16(pa0, b0, o_acc[n], 0, 0, 0);
            o_acc[n] = __builtin_amdgcn_mfma_f32_16x16x32_f16(pa1, b1, o_acc[n], 0, 0, 0);
        }
    }
    __syncthreads();
    #pragma unroll
    for (int r = 0; r < 4; ++r) {
        float inv = (l_i[r] > 0.f) ? 1.f / l_i[r] : 0.f;
        #pragma unroll
        for (int n = 0; n < 8; ++n)
            k_s[(w16 + quad * 4 + r) * 132 + n * 16 + l15] = f2h(o_acc[n][r] * inv);
    }
    __syncthreads();
    #pragma unroll
    for (int it = 0; it < 8; ++it) {
        int idx = t + it * 256;
        int r = idx >> 5, cpos = (idx & 31) * 4;
        *(ushort4*)&Og[(size_t)(b * 2048 + q0 + r) * 2048 + h * 128 + cpos] =
            *(ushort4*)&k_s[r * 132 + cpos];
    }
}

// ---------- launch ----------
extern "C" void kernel_launch(void* const* d_in, const int* in_sizes, int n_in,
                              void* d_out, int out_size, void* d_ws, size_t ws_size,
                              hipStream_t stream) {
    const float* hs = (const float*)d_in[0];
    const float* wq = (const float*)d_in[1];
    const float* wk = (const float*)d_in[2];
    const float* wv = (const float*)d_in[3];
    const float* wo = (const float*)d_in[4];
    float* out = (float*)d_out;
    char* ws = (char*)d_ws;

    // phase-1 (gate) buffers, overlapped with the Cqkv region:
    double*         Act  = (double*)       (ws + 37748736);    // 16.78 MB
    double*         Ast  = (double*)       (ws + 54525952);    // 16.78 MB
    // phase-2 buffers:
    unsigned short* hsh  = (unsigned short*)(ws + 0);          // 16.78 MB
    unsigned short* Wth  = (unsigned short*)(ws + 16777216);   // 12.58 MB
    unsigned short* woth = (unsigned short*)(ws + 29360128);   //  8.39 MB
    float*          Cqkv = (float*)        (ws + 37748736);    // 50.33 MB
    unsigned short* Og   = (unsigned short*)(ws + 88080384);   // 16.78 MB
    // persistent:
    double*         km64 = (double*)       (ws + 104857600);   // 64 KB
    unsigned int*   mskb = (unsigned int*) (ws + 104923136);   // 512 KB
    float*          ct   = (float*)        (ws + 105447424);   // 512 KB
    float*          st   = (float*)        (ws + 105971712);   // 512 KB
    unsigned short* Kh   = (unsigned short*)(ws + 106496000);  //  8.39 MB
    unsigned short* Vt   = (unsigned short*)(ws + 114884608);  //  8.39 MB
    int*            fcnt = (int*)          (ws + 123273216);   // 64 B (16 ints)
    int*            flst = (int*)          (ws + 123273280);   // 256 KB (16 x 4096)

    fused0_kernel <<<18944, 256, 0, stream>>>(ct, st, km64, fcnt, hs, hsh,
                                              wq, wk, wv, wo, Wth, woth);
    ksum_kernel   <<<dim3(32, 16), 256, 0, stream>>>(hs, ct, st, Act, Ast);
    kmeanw_kernel <<<2048, 256, 0, stream>>>(Act, Ast, wk, km64);
    gemm_kernel   <<<dim3(24, 32), 256, 0, stream>>>(hsh, Wth, Cqkv, 4096, 3072, 2048);
    ropegate_kernel<<<4096, 256, 0, stream>>>(Cqkv, ct, st, km64, mskb, fcnt, flst);
    fusedrk_kernel<<<4352, 256, 0, stream>>>(hs, wq, ct, st, km64, fcnt, flst, mskb,
                                             Cqkv, Kh, Vt);
    attn_kernel   <<<1024, 256, 0, stream>>>(Cqkv, Kh, Vt, mskb, Og);
    gemm_kernel   <<<dim3(16, 32), 256, 0, stream>>>(Og, woth, out, 4096, 2048, 2048);
}

// Round 21
// 556.637 us; speedup vs baseline: 1.1283x; 1.0044x over previous
//
#include <hip/hip_runtime.h>
#include <stdint.h>
#include <math.h>

// ---------- types / helpers ----------
typedef _Float16 f16x8 __attribute__((ext_vector_type(8)));
typedef float    f32x4 __attribute__((ext_vector_type(4)));
typedef __attribute__((address_space(1))) void as1_void;
typedef __attribute__((address_space(3))) void as3_void;

__device__ __forceinline__ unsigned short f2h(float x) {
    _Float16 h = (_Float16)x;
    return __builtin_bit_cast(unsigned short, h);
}
__device__ __forceinline__ float h2f(unsigned short u) {
    return (float)__builtin_bit_cast(_Float16, u);
}
// async global->LDS, 16B/lane; lds dest must be wave-uniform base (HW adds lane*16)
__device__ __forceinline__ void glds16(const void* g, void* l) {
    __builtin_amdgcn_global_load_lds((as1_void*)g, (as3_void*)l, 16, 0, 0);
}

// 16-lane DPP butterfly step (VALU-speed, avoids ds_swizzle latency of __shfl_xor):
// 0xB1 = quad_perm(1,0,3,2) ~ xor1 ; 0x4E = quad_perm(2,3,0,1) ~ xor2 ;
// 0x141 = row_half_mirror (pairs across quads within 8) ; 0x128 = row_ror:8 ~ xor8.
#define DPPF(v, ctrl) __builtin_bit_cast(float, \
    __builtin_amdgcn_update_dpp(0, __builtin_bit_cast(int, (v)), (ctrl), 0xF, 0xF, true))

// B=2, S=2048, Hid=2048, NH=16, NKV=4, D=128, chunks: 8 x 256, TOPK=4
//
// FINAL (session best, measured 559.1us at R19):
//  - DPP 16-lane softmax (R4), kmeanw ILP+grid fix (R5), repair LDS/ILP +
//    h-bucketed L2 locality (R6/R8), ropegate 8-lane-group reduce (R11),
//    R13 wave-skip (bit-exact), R15 fusions (8 launches).
//  - Closed by measurement: 32-rows/wave (R9 occupancy / R10 spill),
//    V-direct-from-global (R17: exposed L2 latency in PV chain),
//    128-row Q tile (R3 spill). attn's limiter = 2-barrier staging cadence.
//
// VGPR discipline (R3+R10): live-VGPR must fit 512/(waves-per-EU bound);
// spill signature = WRITE_SIZE blowup + forced-low VGPR_Count.

#define TAU 0.015
#define FLAGCAP 4096

// ---------- fused0: setup | split | packall ----------
// grid: [0,512) setup ; [512,8704) split ; [8704,18944) packall
__global__ __launch_bounds__(256)
void fused0_kernel(float* __restrict__ ct, float* __restrict__ st,
                   double* __restrict__ km, int* __restrict__ flagcnt,
                   const float* __restrict__ hs, unsigned short* __restrict__ hsh,
                   const float* __restrict__ wq, const float* __restrict__ wk,
                   const float* __restrict__ wv, const float* __restrict__ wo,
                   unsigned short* __restrict__ Wh, unsigned short* __restrict__ Woh) {
    int bid = blockIdx.x;
    int t = threadIdx.x;
    if (bid < 512) {
        // ---- setup: CR-fp32 sincos tables + zero km64 + zero flag counters
        int gid = bid * 256 + t;            // 512*256 = 2048*64
        if (gid < 16) flagcnt[gid] = 0;
        if (gid < 8192) km[gid] = 0.0;
        int i = gid & 63, s = gid >> 6;
        float xf = (float)i * (1.0f / 64.0f);
        float pf = (float)pow(10000.0, (double)xf);     // CR fp32 pow
        float inv = 1.0f / pf;                          // second fp32 rounding (np)
        float ang = (float)s * inv;
        ct[gid] = (float)cos((double)ang);
        st[gid] = (float)sin((double)ang);
    } else if (bid < 8704) {
        // ---- split: hs fp32 -> fp16 (2097152 float4 groups)
        int i = (bid - 512) * 256 + t;
        if (i >= 2097152) return;
        float4 v = ((const float4*)hs)[i];
        ushort4 h;
        h.x = f2h(v.x); h.y = f2h(v.y); h.z = f2h(v.z); h.w = f2h(v.w);
        ((ushort4*)hsh)[i] = h;
    } else {
        // ---- packall: [wq|wk|wv]^T -> Wh[n][k], wo^T -> Woh[n][k], fp16
        int gid = (bid - 8704) * 256 + t;
        if (gid < 3072 * 512) {
            int n  = gid % 3072;
            int kg = gid / 3072;
            const float* src; int ldn, col;
            if (n < 2048)      { src = wq; ldn = 2048; col = n; }
            else if (n < 2560) { src = wk; ldn = 512;  col = n - 2048; }
            else               { src = wv; ldn = 512;  col = n - 2560; }
            int k0 = kg * 4;
            ushort4 h;
            h.x = f2h(src[(size_t)(k0 + 0) * ldn + col]);
            h.y = f2h(src[(size_t)(k0 + 1) * ldn + col]);
            h.z = f2h(src[(size_t)(k0 + 2) * ldn + col]);
            h.w = f2h(src[(size_t)(k0 + 3) * ldn + col]);
            *(ushort4*)&Wh[(size_t)n * 2048 + k0] = h;
        } else {
            int g2 = gid - 3072 * 512;   // 2048*512
            int n  = g2 % 2048;
            int kg = g2 / 2048;
            int k0 = kg * 4;
            ushort4 h;
            h.x = f2h(wo[(size_t)(k0 + 0) * 2048 + n]);
            h.y = f2h(wo[(size_t)(k0 + 1) * 2048 + n]);
            h.z = f2h(wo[(size_t)(k0 + 2) * 2048 + n]);
            h.w = f2h(wo[(size_t)(k0 + 3) * 2048 + n]);
            *(ushort4*)&Woh[(size_t)n * 2048 + k0] = h;
        }
    }
}

// ---------- trig-weighted chunk sums: Act/Ast[bn][h][d] (fp64) ----------
__global__ __launch_bounds__(256)
void ksum_kernel(const float* __restrict__ hs, const float* __restrict__ ct,
                 const float* __restrict__ st, double* __restrict__ Act,
                 double* __restrict__ Ast) {
    __shared__ float Hs[16][68];
    __shared__ float Tc[16][68];
    __shared__ float Ts[16][68];
    int bn = blockIdx.y;             // b*8 + n
    int h0 = blockIdx.x * 64;
    int b = bn >> 3, n = bn & 7;
    int t = threadIdx.x;
    int tx = t & 15, ty = t >> 4;
    int d0 = tx * 4, hl0 = ty * 4;
    int si = t & 15, g4 = (t >> 4) * 4;
    double ac[4][4] = {}, as_[4][4] = {};
    for (int s0 = 0; s0 < 256; s0 += 16) {
        __syncthreads();
        int srow = n * 256 + s0 + si;
        *(float4*)&Hs[si][g4] = *(const float4*)&hs[(size_t)(b * 2048 + srow) * 2048 + h0 + g4];
        *(float4*)&Tc[si][g4] = *(const float4*)&ct[srow * 64 + g4];
        *(float4*)&Ts[si][g4] = *(const float4*)&st[srow * 64 + g4];
        __syncthreads();
        #pragma unroll
        for (int kk = 0; kk < 16; ++kk) {
            double hv[4], cv[4], sv[4];
            #pragma unroll
            for (int j = 0; j < 4; ++j) hv[j] = (double)Hs[kk][hl0 + j];
            #pragma unroll
            for (int i = 0; i < 4; ++i) { cv[i] = (double)Tc[kk][d0 + i]; sv[i] = (double)Ts[kk][d0 + i]; }
            #pragma unroll
            for (int i = 0; i < 4; ++i)
                #pragma unroll
                for (int j = 0; j < 4; ++j) {
                    ac[i][j]  = fma(cv[i], hv[j], ac[i][j]);
                    as_[i][j] = fma(sv[i], hv[j], as_[i][j]);
                }
        }
    }
    #pragma unroll
    for (int j = 0; j < 4; ++j) {
        size_t rb = ((size_t)bn * 2048 + h0 + hl0 + j) * 64 + d0;
        double2 c0 = {ac[0][j], ac[1][j]},  c1 = {ac[2][j], ac[3][j]};
        double2 s0_ = {as_[0][j], as_[1][j]}, s1_ = {as_[2][j], as_[3][j]};
        *(double2*)&Act[rb] = c0; *(double2*)&Act[rb + 2] = c1;
        *(double2*)&Ast[rb] = s0_; *(double2*)&Ast[rb + 2] = s1_;
    }
}

// ---------- contract Act/Ast with wk -> exact km64 ----------
__global__ __launch_bounds__(256)
void kmeanw_kernel(const double* __restrict__ Act, const double* __restrict__ Ast,
                   const float* __restrict__ wk, double* __restrict__ km) {
    __shared__ double red[256];
    int blk = blockIdx.x;            // ((bn*4 + kvh)*32 + hp)
    int hp = blk & 31, kvh = (blk >> 5) & 3, bn = blk >> 7;
    int t = threadIdx.x;
    int d = t & 127, sub = t >> 7;
    int jj = d & 63;
    int col1 = kvh * 128 + d;
    int col2 = kvh * 128 + (d ^ 64);
    double sgn = (d < 64) ? -1.0 : 1.0;
    const double* actb = Act + (size_t)bn * 2048 * 64;
    const double* astb = Ast + (size_t)bn * 2048 * 64;
    double a1 = 0.0, a2 = 0.0, b1 = 0.0, b2 = 0.0;
    double c1 = 0.0, c2 = 0.0, d1 = 0.0, d2 = 0.0;
    int hbeg = hp * 64 + sub * 32;   // 32 hp x 64 + 2 sub x 32 covers [0,2048)
    #pragma unroll 2
    for (int h = hbeg; h < hbeg + 32; h += 4) {
        a1 = fma(actb[(size_t)(h + 0) * 64 + jj], (double)wk[(size_t)(h + 0) * 512 + col1], a1);
        a2 = fma(astb[(size_t)(h + 0) * 64 + jj], (double)wk[(size_t)(h + 0) * 512 + col2], a2);
        b1 = fma(actb[(size_t)(h + 1) * 64 + jj], (double)wk[(size_t)(h + 1) * 512 + col1], b1);
        b2 = fma(astb[(size_t)(h + 1) * 64 + jj], (double)wk[(size_t)(h + 1) * 512 + col2], b2);
        c1 = fma(actb[(size_t)(h + 2) * 64 + jj], (double)wk[(size_t)(h + 2) * 512 + col1], c1);
        c2 = fma(astb[(size_t)(h + 2) * 64 + jj], (double)wk[(size_t)(h + 2) * 512 + col2], c2);
        d1 = fma(actb[(size_t)(h + 3) * 64 + jj], (double)wk[(size_t)(h + 3) * 512 + col1], d1);
        d2 = fma(astb[(size_t)(h + 3) * 64 + jj], (double)wk[(size_t)(h + 3) * 512 + col2], d2);
    }
    double acc1 = (a1 + b1) + (c1 + d1);
    double acc2 = (a2 + b2) + (c2 + d2);
    red[t] = acc1 + sgn * acc2;
    __syncthreads();
    if (t < 128) {
        double v = red[t] + red[t + 128];
        atomicAdd(&km[((size_t)bn * 4 + kvh) * 128 + d], v * (1.0 / 256.0));
    }
}

// ---------- fused rope (q,k in-place) + provisional fp64 gates + margin flags ----
// R11: 8-lane-group-per-chunk reduce, 3-step butterfly + 8 gathers.
__global__ __launch_bounds__(256)
void ropegate_kernel(float* __restrict__ C, const float* __restrict__ ct,
                     const float* __restrict__ st, const double* __restrict__ km,
                     unsigned int* __restrict__ maskbuf,
                     int* __restrict__ flagcnt, int* __restrict__ flaglist) {
    __shared__ float qbuf[2048];
    int bs = blockIdx.x;             // b*2048 + s
    int s = bs & 2047, b = bs >> 11;
    int t = threadIdx.x;
    size_t base = (size_t)bs * 3072;
    #pragma unroll
    for (int it = 0; it < 5; ++it) {  // 20 heads x 64 pairs = 1280 = 5*256
        int p = t + it * 256;
        int hd = p >> 6, i = p & 63;
        float cs = ct[s * 64 + i], sn = st[s * 64 + i];
        float x1 = C[base + hd * 128 + i];
        float x2 = C[base + hd * 128 + i + 64];
        float n1 = x1 * cs - x2 * sn;
        float n2 = x2 * cs + x1 * sn;
        C[base + hd * 128 + i] = n1;
        C[base + hd * 128 + i + 64] = n2;
        if (hd < 16) { qbuf[hd * 128 + i] = n1; qbuf[hd * 128 + i + 64] = n2; }
    }
    __syncthreads();
    int wave = t >> 6, lane = t & 63;
    int grp = lane >> 3, j = lane & 7;   // group -> chunk n, j -> d sub-lane
    int qc = s >> 8;
    const double INF = __builtin_inf();
    #pragma unroll
    for (int ii = 0; ii < 4; ++ii) {
        int h = wave * 4 + ii;
        int kvh = h >> 2;
        size_t kb = (size_t)((b * 8 + grp) * 4 + kvh) * 128;
        const float* qh = qbuf + h * 128;
        double acc0 = 0.0, acc1 = 0.0;
        #pragma unroll
        for (int i = 0; i < 8; ++i) {
            int d = j + 8 * i;
            acc0 = fma((double)qh[d],      km[kb + d],      acc0);
            acc1 = fma((double)qh[d + 64], km[kb + 64 + d], acc1);
        }
        double acc = acc0 + acc1;
        // 3-step butterfly within the 8-lane group (chunk-local sum)
        acc += __shfl_xor(acc, 1);
        acc += __shfl_xor(acc, 2);
        acc += __shfl_xor(acc, 4);
        // gather group sums: g[n] lives in lanes n*8..n*8+7
        double g[8];
        #pragma unroll
        for (int n = 0; n < 8; ++n) g[n] = __shfl(acc, n * 8);
        #pragma unroll
        for (int n = 0; n < 8; ++n) {
            if (n == qc)                g[n] = INF;
            else if (s < (n + 1) * 256) g[n] = -INF;
        }
        unsigned int msk = 0;
        for (int p = 0; p < 4; ++p) {  // iterative argmax; strict > => lowest idx on ties
            double best = -INF; int bi = -1;
            #pragma unroll
            for (int n = 0; n < 8; ++n)
                if (!((msk >> n) & 1) && g[n] > best) { best = g[n]; bi = n; }
            if (bi >= 0) msk |= 1u << bi;
        }
        if (lane == 0) {
            int wid = ((b * 16 + h) << 11) + s;
            maskbuf[wid] = msk;
            if (qc >= 4) {
                double worst_in = INF, best_out = -INF;
                #pragma unroll
                for (int n = 0; n < 8; ++n) {
                    if ((msk >> n) & 1) worst_in = fmin(worst_in, g[n]);
                    else if (g[n] > -1e300) best_out = fmax(best_out, g[n]);
                }
                if (worst_in - best_out < TAU) {
                    int ix = atomicAdd(&flagcnt[h], 1);
                    if (ix < FLAGCAP) flaglist[h * FLAGCAP + ix] = wid;
                }
            }
        }
    }
}

// ---------- fusedrk: repair (h-bucketed) | kvprep ----------
// grid: [0,4096) repair ; [4096,4352) kvprep. LDS union = 25856B (repair's
// footprint) -> repair occupancy unchanged; kvprep's 18432B fits inside.
__global__ __launch_bounds__(256)
void fusedrk_kernel(const float* __restrict__ hs, const float* __restrict__ wq,
                    const float* __restrict__ ct, const float* __restrict__ st,
                    const double* __restrict__ km, const int* __restrict__ flagcnt,
                    const int* __restrict__ flaglist, unsigned int* __restrict__ maskbuf,
                    const float* __restrict__ C, unsigned short* __restrict__ Kh,
                    unsigned short* __restrict__ Vt) {
    __shared__ char SH[25856];
    int t = threadIdx.x;
    if (blockIdx.x < 4096) {
        // ---- repair path (R5 ILP + R6 h-bucketing)
        double* hrow_d = (double*)SH;                       // 2048 d = 16384B
        double (*red)[132] = (double(*)[132])(SH + 16384);  // 8x132 d = 8448B
        double* qs = (double*)(SH + 24832);                 // 128 d = 1024B
        int hb = blockIdx.x >> 8;         // 16 head groups x 256 blocks
        int nflag = flagcnt[hb];
        if (nflag > FLAGCAP) nflag = FLAGCAP;
        const int* list = flaglist + hb * FLAGCAP;
        int dg = t & 31, sub = t >> 5;    // d = dg*4..+3 ; k in [sub*256, +256)
        for (int idx = blockIdx.x & 255; idx < nflag; idx += 256) {
            int wid = list[idx];
            int s = wid & 2047;
            int h = (wid >> 11) & 15;
            int b = wid >> 15;
            int kvh = h >> 2;
            __syncthreads();
            {   // cooperative coalesced fp32->fp64 row stage
                const float4* src = (const float4*)(hs + (size_t)(b * 2048 + s) * 2048);
                float4 v0 = src[t], v1 = src[t + 256];
                hrow_d[4 * t + 0] = (double)v0.x; hrow_d[4 * t + 1] = (double)v0.y;
                hrow_d[4 * t + 2] = (double)v0.z; hrow_d[4 * t + 3] = (double)v0.w;
                hrow_d[4 * t + 1024 + 0] = (double)v1.x; hrow_d[4 * t + 1024 + 1] = (double)v1.y;
                hrow_d[4 * t + 1024 + 2] = (double)v1.z; hrow_d[4 * t + 1024 + 3] = (double)v1.w;
            }
            __syncthreads();
            const float* wbase = wq + (size_t)(sub * 256) * 2048 + h * 128 + dg * 4;
            const double* hb_ = hrow_d + sub * 256;
            double a0 = 0, a1 = 0, a2 = 0, a3 = 0;
            double c0 = 0, c1 = 0, c2 = 0, c3 = 0;
            #pragma unroll 4
            for (int k = 0; k < 256; k += 2) {
                float4 w0 = *(const float4*)&wbase[(size_t)k * 2048];
                float4 w1 = *(const float4*)&wbase[(size_t)(k + 1) * 2048];
                double h0 = hb_[k], h1 = hb_[k + 1];
                a0 = fma(h0, (double)w0.x, a0); a1 = fma(h0, (double)w0.y, a1);
                a2 = fma(h0, (double)w0.z, a2); a3 = fma(h0, (double)w0.w, a3);
                c0 = fma(h1, (double)w1.x, c0); c1 = fma(h1, (double)w1.y, c1);
                c2 = fma(h1, (double)w1.z, c2); c3 = fma(h1, (double)w1.w, c3);
            }
            red[sub][dg * 4 + 0] = a0 + c0; red[sub][dg * 4 + 1] = a1 + c1;
            red[sub][dg * 4 + 2] = a2 + c2; red[sub][dg * 4 + 3] = a3 + c3;
            __syncthreads();
            if (t < 128) {
                double v = 0.0;
                #pragma unroll
                for (int u = 0; u < 8; ++u) v += red[u][t];
                qs[t] = v;
            }
            __syncthreads();
            if (t < 64) {
                double c  = (double)ct[s * 64 + t];
                double sn = (double)st[s * 64 + t];
                double x1 = qs[t], x2 = qs[t + 64];
                qs[t]      = x1 * c - x2 * sn;
                qs[t + 64] = x2 * c + x1 * sn;
            }
            __syncthreads();
            if (t < 64) {
                double g[8];
                #pragma unroll
                for (int n = 0; n < 8; ++n) {
                    size_t kb = (size_t)((b * 8 + n) * 4 + kvh) * 128;
                    double v = qs[t] * km[kb + t] + qs[t + 64] * km[kb + 64 + t];
                    #pragma unroll
                    for (int off = 32; off; off >>= 1) v += __shfl_xor(v, off);
                    g[n] = v;
                }
                int qc = s >> 8;
                const double INF = __builtin_inf();
                #pragma unroll
                for (int n = 0; n < 8; ++n) {
                    if (n == qc)                g[n] = INF;
                    else if (s < (n + 1) * 256) g[n] = -INF;
                }
                unsigned int msk = 0;
                for (int p = 0; p < 4; ++p) {
                    double best = -INF; int bi = -1;
                    #pragma unroll
                    for (int n = 0; n < 8; ++n)
                        if (!((msk >> n) & 1) && g[n] > best) { best = g[n]; bi = n; }
                    if (bi >= 0) msk |= 1u << bi;
                }
                if (t == 0) maskbuf[wid] = msk;
            }
            __syncthreads();
        }
    } else {
        // ---- kvprep path: K -> fp16 row-major, V -> fp16 transposed
        unsigned short (*vt)[72] = (unsigned short(*)[72])SH;   // 128x72 us = 18432B
        int blk = blockIdx.x - 4096;   // (b*4+kvh)*32 + kt
        int kt = blk & 31, kvh = (blk >> 5) & 3, b = blk >> 7;
        int key0 = kt * 64;
        #pragma unroll
        for (int it = 0; it < 8; ++it) {
            int idx = t + it * 256;
            int r = idx >> 5, c = (idx & 31) * 4;
            size_t rowb = (size_t)(b * 2048 + key0 + r) * 3072;
            float4 kv = *(const float4*)&C[rowb + 2048 + kvh * 128 + c];
            ushort4 u; u.x = f2h(kv.x); u.y = f2h(kv.y); u.z = f2h(kv.z); u.w = f2h(kv.w);
            *(ushort4*)&Kh[((size_t)(b * 4 + kvh) * 2048 + key0 + r) * 128 + c] = u;
            float4 vv = *(const float4*)&C[rowb + 2560 + kvh * 128 + c];
            vt[c + 0][r] = f2h(vv.x); vt[c + 1][r] = f2h(vv.y);
            vt[c + 2][r] = f2h(vv.z); vt[c + 3][r] = f2h(vv.w);
        }
        __syncthreads();
        #pragma unroll
        for (int it = 0; it < 8; ++it) {
            int idx = t + it * 256;
            int d = idx >> 4, c4 = (idx & 15) * 4;
            *(ushort4*)&Vt[((size_t)(b * 4 + kvh) * 128 + d) * 2048 + key0 + c4] =
                *(ushort4*)&vt[d][c4];
        }
    }
}

// ---------- fp16 MFMA GEMM, m97-style global_load_lds staging ----------
// A row-major [m][k]; B pre-transposed [n][k]; unpadded LDS tiles [128][32].
__global__ __launch_bounds__(256, 2)
void gemm_kernel(const unsigned short* __restrict__ A_g, const unsigned short* __restrict__ B_g,
                 float* __restrict__ Cg, int M, int N, int K) {
    __shared__ unsigned short Ah[128 * 32];
    __shared__ unsigned short Bh[128 * 32];
    int n0 = blockIdx.x * 128, m0 = blockIdx.y * 128;
    int t = threadIdx.x;
    int wave = t >> 6, lane = t & 63;
    int quad = lane >> 4, l15 = lane & 15;
    int wm = (wave >> 1) * 64, wn = (wave & 1) * 64;

    f32x4 acc[4][4];
    f32x4 zero = {0.f, 0.f, 0.f, 0.f};
    for (int i = 0; i < 4; ++i)
        for (int j = 0; j < 4; ++j) acc[i][j] = zero;

    // staging: lane covers row (lane>>2), 8 halves at col (lane&3)*8 of a 16-row segment
    int srow = lane >> 2, scol = (lane & 3) * 8;
    const unsigned short* Ag0 = &A_g[(size_t)(m0 + wave * 16 + srow) * K + scol];
    const unsigned short* Ag1 = &A_g[(size_t)(m0 + 64 + wave * 16 + srow) * K + scol];
    const unsigned short* Bg0 = &B_g[(size_t)(n0 + wave * 16 + srow) * K + scol];
    const unsigned short* Bg1 = &B_g[(size_t)(n0 + 64 + wave * 16 + srow) * K + scol];
    unsigned short* Al0 = &Ah[(wave * 16) * 32];
    unsigned short* Al1 = &Ah[(64 + wave * 16) * 32];
    unsigned short* Bl0 = &Bh[(wave * 16) * 32];
    unsigned short* Bl1 = &Bh[(64 + wave * 16) * 32];

    for (int k0 = 0; k0 < K; k0 += 32) {
        __syncthreads();
        glds16(Ag0 + k0, Al0);
        glds16(Ag1 + k0, Al1);
        glds16(Bg0 + k0, Bl0);
        glds16(Bg1 + k0, Bl1);
        __syncthreads();   // drains vmcnt -> staging visible
        f16x8 ah[4], bh[4];
        #pragma unroll
        for (int i = 0; i < 4; ++i) {
            ah[i] = *(const f16x8*)&Ah[(wm + i * 16 + l15) * 32 + quad * 8];
            bh[i] = *(const f16x8*)&Bh[(wn + i * 16 + l15) * 32 + quad * 8];
        }
        #pragma unroll
        for (int i = 0; i < 4; ++i)
            #pragma unroll
            for (int j = 0; j < 4; ++j)
                acc[i][j] = __builtin_amdgcn_mfma_f32_16x16x32_f16(ah[i], bh[j], acc[i][j], 0, 0, 0);
    }
    #pragma unroll
    for (int i = 0; i < 4; ++i)
        #pragma unroll
        for (int j = 0; j < 4; ++j)
            #pragma unroll
            for (int r = 0; r < 4; ++r) {
                int row = m0 + wm + i * 16 + quad * 4 + r;
                int col = n0 + wn + j * 16 + l15;
                Cg[(size_t)row * N + col] = acc[i][j][r];
            }
}

// ---------- MFMA flash attention: LDS-staged, register-prefetch pipelined ----------
// R13: wave-level subtile skip (bit-exact, barrier-safe).
__global__ __launch_bounds__(256, 3)
void attn_kernel(const float* __restrict__ C, const unsigned short* __restrict__ Kh,
                 const unsigned short* __restrict__ Vt,
                 const unsigned int* __restrict__ maskbuf,
                 unsigned short* __restrict__ Og) {
    __shared__ unsigned short qv[8704];   // Q [64][132] -> V^T [128][68]
    __shared__ unsigned short k_s[8448];  // K [64][132]; output staging at end
    __shared__ unsigned short p_s[4352];  // P [64][68]
    __shared__ int kb_list[32];
    __shared__ int nsub_s;
    __shared__ unsigned int umask;

    int bid = blockIdx.x;
    int qt = 31 - (bid >> 5);             // longest-work-first
    int bh = bid & 31;
    int h = bh & 15, b = bh >> 4;
    int t = threadIdx.x;
    int wave = t >> 6, lane = t & 63;
    int quad = lane >> 4, l15 = lane & 15;
    int w16 = wave * 16;
    int q0 = qt * 64, qc = q0 >> 8, kvh = h >> 2;
    const float NEGINF = -__builtin_inff();

    #pragma unroll
    for (int it = 0; it < 8; ++it) {
        int idx = t + it * 256;
        int r = idx >> 5, c = (idx & 31) * 4;
        float4 v4 = *(const float4*)&C[(size_t)(b * 2048 + q0 + r) * 3072 + h * 128 + c];
        ushort4 u; u.x = f2h(v4.x); u.y = f2h(v4.y); u.z = f2h(v4.z); u.w = f2h(v4.w);
        *(ushort4*)&qv[r * 132 + c] = u;
    }
    if (t == 0) umask = 0;
    int mbase = ((b * 16 + h) << 11) + q0;
    unsigned int am[4];
    #pragma unroll
    for (int r = 0; r < 4; ++r)
        am[r] = maskbuf[mbase + w16 + quad * 4 + r];
    // wave-union mask: OR over this wave's 16 rows (2 shuffles across quads)
    unsigned int wam = am[0] | am[1] | am[2] | am[3];
    wam |= __shfl_xor((int)wam, 16);
    wam |= __shfl_xor((int)wam, 32);
    __syncthreads();
    if (t < 64) atomicOr(&umask, maskbuf[mbase + t]);
    f16x8 aq[4];
    #pragma unroll
    for (int ks = 0; ks < 4; ++ks)
        aq[ks] = *(const f16x8*)&qv[(w16 + l15) * 132 + ks * 32 + quad * 8];
    __syncthreads();
    if (t == 0) {
        unsigned int um = umask;
        int n = 0;
        for (int c = 0; c <= qc; ++c) {
            if (!((um >> c) & 1)) continue;
            int submax = (c == qc) ? ((q0 & 255) >> 6) : 3;
            for (int sub = 0; sub <= submax; ++sub) kb_list[n++] = c * 256 + sub * 64;
        }
        nsub_s = n;
    }
    __syncthreads();
    int nsub = nsub_s;

    float m_i[4], l_i[4];
    f32x4 o_acc[8];
    #pragma unroll
    for (int r = 0; r < 4; ++r) { m_i[r] = NEGINF; l_i[r] = 0.f; }
    #pragma unroll
    for (int n = 0; n < 8; ++n) o_acc[n] = (f32x4){0.f, 0.f, 0.f, 0.f};
    const float scale = 0.08838834764831845f;
    const unsigned short* Kb = Kh + (size_t)(b * 4 + kvh) * 2048 * 128;
    const unsigned short* Vb = Vt + (size_t)(b * 4 + kvh) * 128 * 2048;

    int kr = t >> 5, kc = (t & 31) * 4;
    int vr = t >> 4, vc = (t & 15) * 4;

    ushort4 kpre[8], vpre[8];
    {
        int kb0 = kb_list[0];
        #pragma unroll
        for (int it = 0; it < 8; ++it) {
            kpre[it] = *(const ushort4*)&Kb[(size_t)(kb0 + kr + it * 8) * 128 + kc];
            vpre[it] = *(const ushort4*)&Vb[(size_t)(vr + it * 16) * 2048 + kb0 + vc];
        }
    }

    for (int i = 0; i < nsub; ++i) {
        int kbase = kb_list[i];
        __syncthreads();
        #pragma unroll
        for (int it = 0; it < 8; ++it) {
            *(ushort4*)&k_s[(kr + it * 8) * 132 + kc] = kpre[it];
            *(ushort4*)&qv[(vr + it * 16) * 68 + vc] = vpre[it];
        }
        __syncthreads();
        if (i + 1 < nsub) {
            int kbn = kb_list[i + 1];
            #pragma unroll
            for (int it = 0; it < 8; ++it) {
                kpre[it] = *(const ushort4*)&Kb[(size_t)(kbn + kr + it * 8) * 128 + kc];
                vpre[it] = *(const ushort4*)&Vb[(size_t)(vr + it * 16) * 2048 + kbn + vc];
            }
        }
        // wave-level skip: contribution provably zero (wave-uniform branch)
        bool wskip = !((wam >> (kbase >> 8)) & 1) || (kbase > q0 + w16 + 15);
        if (wskip) continue;
        f32x4 s[4];
        #pragma unroll
        for (int j = 0; j < 4; ++j) {
            f32x4 sj = {0.f, 0.f, 0.f, 0.f};
            #pragma unroll
            for (int ks = 0; ks < 4; ++ks) {
                f16x8 bf = *(const f16x8*)&k_s[(j * 16 + l15) * 132 + ks * 32 + quad * 8];
                sj = __builtin_amdgcn_mfma_f32_16x16x32_f16(aq[ks], bf, sj, 0, 0, 0);
            }
            s[j] = sj;
        }
        #pragma unroll
        for (int r = 0; r < 4; ++r) {
            int qpos = q0 + w16 + quad * 4 + r;
            bool allow = (am[r] >> (kbase >> 8)) & 1;
            float sv[4], rmax = NEGINF;
            #pragma unroll
            for (int j = 0; j < 4; ++j) {
                int kpos = kbase + j * 16 + l15;
                float x = s[j][r] * scale;
                if (!allow || kpos > qpos) x = NEGINF;
                sv[j] = x;
                rmax = fmaxf(rmax, x);
            }
            // 16-lane DPP butterfly max (replaces 4 ds_swizzle shfl_xor steps)
            rmax = fmaxf(rmax, DPPF(rmax, 0xB1));
            rmax = fmaxf(rmax, DPPF(rmax, 0x4E));
            rmax = fmaxf(rmax, DPPF(rmax, 0x141));
            rmax = fmaxf(rmax, DPPF(rmax, 0x128));
            float mnew = fmaxf(m_i[r], rmax);
            float alpha = (m_i[r] == NEGINF) ? 0.f : __expf(m_i[r] - mnew);
            float ps[4], lsum = 0.f;
            #pragma unroll
            for (int j = 0; j < 4; ++j) {
                float p = (sv[j] == NEGINF) ? 0.f : __expf(sv[j] - mnew);
                ps[j] = p; lsum += p;
            }
            // 16-lane DPP butterfly sum
            lsum += DPPF(lsum, 0xB1);
            lsum += DPPF(lsum, 0x4E);
            lsum += DPPF(lsum, 0x141);
            lsum += DPPF(lsum, 0x128);
            l_i[r] = l_i[r] * alpha + lsum;
            m_i[r] = mnew;
            #pragma unroll
            for (int n = 0; n < 8; ++n) o_acc[n][r] *= alpha;
            #pragma unroll
            for (int j = 0; j < 4; ++j)
                p_s[(w16 + quad * 4 + r) * 68 + j * 16 + l15] = f2h(ps[j]);
        }
        f16x8 pa0 = *(const f16x8*)&p_s[(w16 + l15) * 68 + quad * 8];
        f16x8 pa1 = *(const f16x8*)&p_s[(w16 + l15) * 68 + 32 + quad * 8];
        #pragma unroll
        for (int n = 0; n < 8; ++n) {
            f16x8 b0 = *(const f16x8*)&qv[(n * 16 + l15) * 68 + quad * 8];
            f16x8 b1 = *(const f16x8*)&qv[(n * 16 + l15) * 68 + 32 + quad * 8];
            o_acc[n] = __builtin_amdgcn_mfma_f32_16x16x32_f16(pa0, b0, o_acc[n], 0, 0, 0);
            o_acc[n] = __builtin_amdgcn_mfma_f32_16x16x32_f16(pa1, b1, o_acc[n], 0, 0, 0);
        }
    }
    __syncthreads();
    #pragma unroll
    for (int r = 0; r < 4; ++r) {
        float inv = (l_i[r] > 0.f) ? 1.f / l_i[r] : 0.f;
        #pragma unroll
        for (int n = 0; n < 8; ++n)
            k_s[(w16 + quad * 4 + r) * 132 + n * 16 + l15] = f2h(o_acc[n][r] * inv);
    }
    __syncthreads();
    #pragma unroll
    for (int it = 0; it < 8; ++it) {
        int idx = t + it * 256;
        int r = idx >> 5, cpos = (idx & 31) * 4;
        *(ushort4*)&Og[(size_t)(b * 2048 + q0 + r) * 2048 + h * 128 + cpos] =
            *(ushort4*)&k_s[r * 132 + cpos];
    }
}

// ---------- launch ----------
extern "C" void kernel_launch(void* const* d_in, const int* in_sizes, int n_in,
                              void* d_out, int out_size, void* d_ws, size_t ws_size,
                              hipStream_t stream) {
    const float* hs = (const float*)d_in[0];
    const float* wq = (const float*)d_in[1];
    const float* wk = (const float*)d_in[2];
    const float* wv = (const float*)d_in[3];
    const float* wo = (const float*)d_in[4];
    float* out = (float*)d_out;
    char* ws = (char*)d_ws;

    // phase-1 (gate) buffers, overlapped with the Cqkv region:
    double*         Act  = (double*)       (ws + 37748736);    // 16.78 MB
    double*         Ast  = (double*)       (ws + 54525952);    // 16.78 MB
    // phase-2 buffers:
    unsigned short* hsh  = (unsigned short*)(ws + 0);          // 16.78 MB
    unsigned short* Wth  = (unsigned short*)(ws + 16777216);   // 12.58 MB
    unsigned short* woth = (unsigned short*)(ws + 29360128);   //  8.39 MB
    float*          Cqkv = (float*)        (ws + 37748736);    // 50.33 MB
    unsigned short* Og   = (unsigned short*)(ws + 88080384);   // 16.78 MB
    // persistent:
    double*         km64 = (double*)       (ws + 104857600);   // 64 KB
    unsigned int*   mskb = (unsigned int*) (ws + 104923136);   // 512 KB
    float*          ct   = (float*)        (ws + 105447424);   // 512 KB
    float*          st   = (float*)        (ws + 105971712);   // 512 KB
    unsigned short* Kh   = (unsigned short*)(ws + 106496000);  //  8.39 MB
    unsigned short* Vt   = (unsigned short*)(ws + 114884608);  //  8.39 MB
    int*            fcnt = (int*)          (ws + 123273216);   // 64 B (16 ints)
    int*            flst = (int*)          (ws + 123273280);   // 256 KB (16 x 4096)

    fused0_kernel <<<18944, 256, 0, stream>>>(ct, st, km64, fcnt, hs, hsh,
                                              wq, wk, wv, wo, Wth, woth);
    ksum_kernel   <<<dim3(32, 16), 256, 0, stream>>>(hs, ct, st, Act, Ast);
    kmeanw_kernel <<<2048, 256, 0, stream>>>(Act, Ast, wk, km64);
    gemm_kernel   <<<dim3(24, 32), 256, 0, stream>>>(hsh, Wth, Cqkv, 4096, 3072, 2048);
    ropegate_kernel<<<4096, 256, 0, stream>>>(Cqkv, ct, st, km64, mskb, fcnt, flst);
    fusedrk_kernel<<<4352, 256, 0, stream>>>(hs, wq, ct, st, km64, fcnt, flst, mskb,
                                             Cqkv, Kh, Vt);
    attn_kernel   <<<1024, 256, 0, stream>>>(Cqkv, Kh, Vt, mskb, Og);
    gemm_kernel   <<<dim3(16, 32), 256, 0, stream>>>(Og, woth, out, 4096, 2048, 2048);
}